// Round 1
// baseline (2165.854 us; speedup 1.0000x reference)
//
#include <hip/hip_runtime.h>
#include <math.h>

#define SEQL   4096
#define DMODEL 1024
#define NH     16
#define DHEAD  64
#define SPOKES 3072
#define NQUERY (SEQL - SPOKES)     // 1024
#define QKVN   (3 * DMODEL)        // 3072

// ---------------------------------------------------------------------------
// GEMM: C[M][N] = A[M][K] * B[N][K]^T   (both row-major, contraction contiguous)
// BM=BN=128, BK=16, 256 threads, 8x8 micro-tile per thread (strided layout).
// ---------------------------------------------------------------------------
__global__ __launch_bounds__(256) void gemm_abt(
    const float* __restrict__ A, const float* __restrict__ B, float* __restrict__ C,
    int M, int N, int K, int lda, int ldb, int ldc)
{
    constexpr int BM = 128, BN = 128, BK = 16, PAD = 5;  // stride 21 (odd) -> conflict-free
    __shared__ float As[BM][BK + PAD];
    __shared__ float Bs[BN][BK + PAD];

    const int t  = threadIdx.x;
    const int tx = t & 15;
    const int ty = t >> 4;
    const int m0 = blockIdx.y * BM;
    const int n0 = blockIdx.x * BN;

    float acc[8][8] = {};

    for (int k0 = 0; k0 < K; k0 += BK) {
        // stage A and B tiles: 128 rows x 16 cols = 512 float4 each
        #pragma unroll
        for (int i = 0; i < 2; ++i) {
            int idx = t + i * 256;
            int row = idx >> 2;
            int c4  = (idx & 3) * 4;
            float4 av = *(const float4*)(A + (size_t)(m0 + row) * lda + k0 + c4);
            As[row][c4 + 0] = av.x; As[row][c4 + 1] = av.y;
            As[row][c4 + 2] = av.z; As[row][c4 + 3] = av.w;
            float4 bv = *(const float4*)(B + (size_t)(n0 + row) * ldb + k0 + c4);
            Bs[row][c4 + 0] = bv.x; Bs[row][c4 + 1] = bv.y;
            Bs[row][c4 + 2] = bv.z; Bs[row][c4 + 3] = bv.w;
        }
        __syncthreads();

        #pragma unroll
        for (int kk = 0; kk < BK; ++kk) {
            float a[8], b[8];
            #pragma unroll
            for (int i = 0; i < 8; ++i) a[i] = As[ty + 16 * i][kk];
            #pragma unroll
            for (int j = 0; j < 8; ++j) b[j] = Bs[tx + 16 * j][kk];
            #pragma unroll
            for (int i = 0; i < 8; ++i)
                #pragma unroll
                for (int j = 0; j < 8; ++j)
                    acc[i][j] += a[i] * b[j];
        }
        __syncthreads();
    }

    #pragma unroll
    for (int i = 0; i < 8; ++i)
        #pragma unroll
        for (int j = 0; j < 8; ++j)
            C[(size_t)(m0 + ty + 16 * i) * ldc + n0 + tx + 16 * j] = acc[i][j];
}

// ---------------------------------------------------------------------------
// In-place cos-scale + axial RoPE on q and k inside the qkv buffer.
// One wave per (l, h) row; lane = dim d in [0,64).
// ---------------------------------------------------------------------------
__global__ __launch_bounds__(256) void transform_qk(
    float* __restrict__ qkv, const float* __restrict__ pos,
    const float* __restrict__ scale, const float* __restrict__ freqs)
{
    const int w    = threadIdx.x >> 6;
    const int lane = threadIdx.x & 63;
    const int rid  = blockIdx.x * 4 + w;      // [0, SEQL*NH)
    const int l    = rid >> 4;
    const int h    = rid & 15;

    float* qp = qkv + (size_t)l * QKVN + h * DHEAD;
    float* kp = qp + DMODEL;

    float q = qp[lane];
    float k = kp[lane];

    float sq = q * q, sk = k * k;
    #pragma unroll
    for (int o = 32; o > 0; o >>= 1) {
        sq += __shfl_xor(sq, o);
        sk += __shfl_xor(sk, o);
    }
    const float ss = sqrtf(fabsf(scale[h]) + 1e-8f);
    q *= ss * rsqrtf(sq + 1e-8f);
    k *= ss * rsqrtf(sk + 1e-8f);

    // theta[j]: j<16 -> (pos_y*2-1)*freqs[1][h][j] ; j>=16 -> (pos_x*2-1)*freqs[0][h][j-16]
    const int   j  = lane & 31;
    const float p  = pos[l * 2 + (j < 16 ? 1 : 0)];
    const float fj = (j < 16) ? freqs[256 + h * 16 + j] : freqs[h * 16 + (j - 16)];
    const float th = (p * 2.0f - 1.0f) * fj;
    const float cs = cosf(th), sn = sinf(th);

    const float qo = __shfl_xor(q, 32);
    const float ko = __shfl_xor(k, 32);
    const float qr = (lane < 32) ? q * cs - qo * sn : q * cs + qo * sn;
    const float kr = (lane < 32) ? k * cs - ko * sn : k * cs + ko * sn;

    qp[lane] = qr;
    kp[lane] = kr;
}

// ---------------------------------------------------------------------------
// Flash attention over pokes (causal, S=3072). One block = (head, 32 q-rows).
// 256 threads as 16x16; thread owns rows {2ty,2ty+1} x score-cols {2tx,2tx+1},
// and output dims {4tx..4tx+3}. Writes result in-place over the q columns.
// ---------------------------------------------------------------------------
__global__ __launch_bounds__(256) void attn_pokes(float* __restrict__ qkv)
{
    __shared__ float Qs[32][65], Ks[32][65], Vs[32][65], Ps[32][33];

    const int h  = blockIdx.y;
    const int qt = blockIdx.x;
    const int q0 = qt * 32;
    const int t  = threadIdx.x;
    const int tx = t & 15;
    const int ty = t >> 4;
    const int qcol = h * DHEAD;
    const int kcol = DMODEL + h * DHEAD;
    const int vcol = 2 * DMODEL + h * DHEAD;

    #pragma unroll
    for (int i = 0; i < 8; ++i) {
        int idx = t + i * 256, r = idx >> 6, d = idx & 63;
        Qs[r][d] = qkv[(size_t)(q0 + r) * QKVN + qcol + d];
    }
    __syncthreads();

    float m_[2]   = {-INFINITY, -INFINITY};
    float lsum[2] = {0.0f, 0.0f};
    float acc[2][4] = {};

    for (int kt = 0; kt <= qt; ++kt) {
        const int k0 = kt * 32;
        #pragma unroll
        for (int i = 0; i < 8; ++i) {
            int idx = t + i * 256, r = idx >> 6, d = idx & 63;
            Ks[r][d] = qkv[(size_t)(k0 + r) * QKVN + kcol + d];
            Vs[r][d] = qkv[(size_t)(k0 + r) * QKVN + vcol + d];
        }
        __syncthreads();

        float s[2][2] = {};
        #pragma unroll 8
        for (int d = 0; d < 64; ++d) {
            float a0 = Qs[2 * ty][d],     a1 = Qs[2 * ty + 1][d];
            float b0 = Ks[2 * tx][d],     b1 = Ks[2 * tx + 1][d];
            s[0][0] += a0 * b0; s[0][1] += a0 * b1;
            s[1][0] += a1 * b0; s[1][1] += a1 * b1;
        }

        if (kt == qt) {
            #pragma unroll
            for (int i = 0; i < 2; ++i)
                #pragma unroll
                for (int jj = 0; jj < 2; ++jj)
                    if (k0 + 2 * tx + jj > q0 + 2 * ty + i) s[i][jj] = -INFINITY;
        }

        #pragma unroll
        for (int i = 0; i < 2; ++i) {
            float rmax = fmaxf(s[i][0], s[i][1]);
            #pragma unroll
            for (int o = 1; o < 16; o <<= 1) rmax = fmaxf(rmax, __shfl_xor(rmax, o));
            const float mnew = fmaxf(m_[i], rmax);
            const float pfac = expf(m_[i] - mnew);   // m_=-INF -> 0 (mnew finite after tile 0)
            float p0 = expf(s[i][0] - mnew);
            float p1 = expf(s[i][1] - mnew);
            Ps[2 * ty + i][2 * tx + 0] = p0;
            Ps[2 * ty + i][2 * tx + 1] = p1;
            float rsum = p0 + p1;
            #pragma unroll
            for (int o = 1; o < 16; o <<= 1) rsum += __shfl_xor(rsum, o);
            lsum[i] = lsum[i] * pfac + rsum;
            m_[i]   = mnew;
            #pragma unroll
            for (int dd = 0; dd < 4; ++dd) acc[i][dd] *= pfac;
        }
        __syncthreads();

        #pragma unroll 4
        for (int c = 0; c < 32; ++c) {
            float p0 = Ps[2 * ty][c], p1 = Ps[2 * ty + 1][c];
            #pragma unroll
            for (int dd = 0; dd < 4; ++dd) {
                float v = Vs[c][4 * tx + dd];
                acc[0][dd] += p0 * v;
                acc[1][dd] += p1 * v;
            }
        }
        __syncthreads();
    }

    #pragma unroll
    for (int i = 0; i < 2; ++i) {
        const float inv = 1.0f / lsum[i];
        #pragma unroll
        for (int dd = 0; dd < 4; ++dd)
            qkv[(size_t)(q0 + 2 * ty + i) * QKVN + qcol + 4 * tx + dd] = acc[i][dd] * inv;
    }
}

// ---------------------------------------------------------------------------
// Query attention: 1024 query rows attend to all 3072 pokes + their own k/v.
// ---------------------------------------------------------------------------
__global__ __launch_bounds__(256) void attn_query(float* __restrict__ qkv)
{
    __shared__ float Qs[32][65], Ks[32][65], Vs[32][65], Ps[32][33];

    const int h  = blockIdx.y;
    const int qt = blockIdx.x;
    const int q0 = SPOKES + qt * 32;
    const int t  = threadIdx.x;
    const int tx = t & 15;
    const int ty = t >> 4;
    const int qcol = h * DHEAD;
    const int kcol = DMODEL + h * DHEAD;
    const int vcol = 2 * DMODEL + h * DHEAD;

    #pragma unroll
    for (int i = 0; i < 8; ++i) {
        int idx = t + i * 256, r = idx >> 6, d = idx & 63;
        Qs[r][d] = qkv[(size_t)(q0 + r) * QKVN + qcol + d];
    }
    __syncthreads();

    // self score  s_self[r] = q_r . k_r   and v_self fragments
    float sself[2];
    float vq[2][4];
    #pragma unroll
    for (int i = 0; i < 2; ++i) {
        const int r = 2 * ty + i;
        float partial = 0.0f;
        #pragma unroll
        for (int dd = 0; dd < 4; ++dd)
            partial += Qs[r][4 * tx + dd] * qkv[(size_t)(q0 + r) * QKVN + kcol + 4 * tx + dd];
        #pragma unroll
        for (int o = 1; o < 16; o <<= 1) partial += __shfl_xor(partial, o);
        sself[i] = partial;
        #pragma unroll
        for (int dd = 0; dd < 4; ++dd)
            vq[i][dd] = qkv[(size_t)(q0 + r) * QKVN + vcol + 4 * tx + dd];
    }

    float m_[2]   = {-INFINITY, -INFINITY};
    float lsum[2] = {0.0f, 0.0f};
    float acc[2][4] = {};

    for (int kt = 0; kt < SPOKES / 32; ++kt) {
        const int k0 = kt * 32;
        #pragma unroll
        for (int i = 0; i < 8; ++i) {
            int idx = t + i * 256, r = idx >> 6, d = idx & 63;
            Ks[r][d] = qkv[(size_t)(k0 + r) * QKVN + kcol + d];
            Vs[r][d] = qkv[(size_t)(k0 + r) * QKVN + vcol + d];
        }
        __syncthreads();

        float s[2][2] = {};
        #pragma unroll 8
        for (int d = 0; d < 64; ++d) {
            float a0 = Qs[2 * ty][d],     a1 = Qs[2 * ty + 1][d];
            float b0 = Ks[2 * tx][d],     b1 = Ks[2 * tx + 1][d];
            s[0][0] += a0 * b0; s[0][1] += a0 * b1;
            s[1][0] += a1 * b0; s[1][1] += a1 * b1;
        }

        #pragma unroll
        for (int i = 0; i < 2; ++i) {
            float rmax = fmaxf(s[i][0], s[i][1]);
            #pragma unroll
            for (int o = 1; o < 16; o <<= 1) rmax = fmaxf(rmax, __shfl_xor(rmax, o));
            const float mnew = fmaxf(m_[i], rmax);
            const float pfac = expf(m_[i] - mnew);
            float p0 = expf(s[i][0] - mnew);
            float p1 = expf(s[i][1] - mnew);
            Ps[2 * ty + i][2 * tx + 0] = p0;
            Ps[2 * ty + i][2 * tx + 1] = p1;
            float rsum = p0 + p1;
            #pragma unroll
            for (int o = 1; o < 16; o <<= 1) rsum += __shfl_xor(rsum, o);
            lsum[i] = lsum[i] * pfac + rsum;
            m_[i]   = mnew;
            #pragma unroll
            for (int dd = 0; dd < 4; ++dd) acc[i][dd] *= pfac;
        }
        __syncthreads();

        #pragma unroll 4
        for (int c = 0; c < 32; ++c) {
            float p0 = Ps[2 * ty][c], p1 = Ps[2 * ty + 1][c];
            #pragma unroll
            for (int dd = 0; dd < 4; ++dd) {
                float v = Vs[c][4 * tx + dd];
                acc[0][dd] += p0 * v;
                acc[1][dd] += p1 * v;
            }
        }
        __syncthreads();
    }

    // fold in the self term, normalize, write in-place over q columns
    #pragma unroll
    for (int i = 0; i < 2; ++i) {
        const float mnew = fmaxf(m_[i], sself[i]);
        const float pf   = expf(m_[i] - mnew);
        const float ps   = expf(sself[i] - mnew);
        const float linv = 1.0f / (lsum[i] * pf + ps);
        #pragma unroll
        for (int dd = 0; dd < 4; ++dd) {
            float o = (acc[i][dd] * pf + ps * vq[i][dd]) * linv;
            qkv[(size_t)(q0 + 2 * ty + i) * QKVN + qcol + 4 * tx + dd] = o;
        }
    }
}

// ---------------------------------------------------------------------------
extern "C" void kernel_launch(void* const* d_in, const int* in_sizes, int n_in,
                              void* d_out, int out_size, void* d_ws, size_t ws_size,
                              hipStream_t stream)
{
    const float* x      = (const float*)d_in[0];
    const float* pos    = (const float*)d_in[1];
    const float* qkv_w  = (const float*)d_in[2];
    const float* out_w  = (const float*)d_in[3];
    const float* scale  = (const float*)d_in[4];
    const float* freqs  = (const float*)d_in[5];
    float*       out    = (float*)d_out;
    float*       qkv    = (float*)d_ws;           // SEQL x 3072 f32 = 48 MB

    const dim3 blk(256);

    // 1) qkv = x @ qkv_w^T
    gemm_abt<<<dim3(QKVN / 128, SEQL / 128), blk, 0, stream>>>(
        x, qkv_w, qkv, SEQL, QKVN, DMODEL, DMODEL, DMODEL, QKVN);

    // 2) cos-scale + axial rope on q,k (in place)
    transform_qk<<<dim3(SEQL * NH / 4), blk, 0, stream>>>(qkv, pos, scale, freqs);

    // 3) causal attention over pokes (writes over q columns)
    attn_pokes<<<dim3(SPOKES / 32, NH), blk, 0, stream>>>(qkv);

    // 4) query attention (pokes + self)
    attn_query<<<dim3(NQUERY / 32, NH), blk, 0, stream>>>(qkv);

    // 5) out = attn @ out_w^T   (attn lives in q columns, lda = 3072)
    gemm_abt<<<dim3(DMODEL / 128, SEQL / 128), blk, 0, stream>>>(
        qkv, out_w, out, SEQL, DMODEL, DMODEL, QKVN, DMODEL, DMODEL);
}

// Round 2
// 808.297 us; speedup vs baseline: 2.6795x; 2.6795x over previous
//
#include <hip/hip_runtime.h>
#include <math.h>

#define SEQL   4096
#define DMODEL 1024
#define NH     16
#define DHEAD  64
#define SPOKES 3072
#define NQUERY (SEQL - SPOKES)     // 1024
#define QKVN   (3 * DMODEL)        // 3072

typedef short bf16x8 __attribute__((ext_vector_type(8)));
typedef float f32x4  __attribute__((ext_vector_type(4)));

__device__ __forceinline__ short f2bf(float f) {
    unsigned u = __builtin_bit_cast(unsigned, f);
    u += 0x7fffu + ((u >> 16) & 1u);     // RNE
    return (short)(u >> 16);
}
// XOR swizzle on bits 4..6 of the byte address, keyed by LDS row.
__device__ __forceinline__ int swz(int row) { return ((row & 7) ^ (row >> 3)) << 4; }

// ---------------------------------------------------------------------------
// GEMM: C[M][N] = A[M][K] * B[N][K]^T   (fp32, unchanged this round)
// ---------------------------------------------------------------------------
__global__ __launch_bounds__(256) void gemm_abt(
    const float* __restrict__ A, const float* __restrict__ B, float* __restrict__ C,
    int M, int N, int K, int lda, int ldb, int ldc)
{
    constexpr int BM = 128, BN = 128, BK = 16, PAD = 5;
    __shared__ float As[BM][BK + PAD];
    __shared__ float Bs[BN][BK + PAD];

    const int t  = threadIdx.x;
    const int tx = t & 15;
    const int ty = t >> 4;
    const int m0 = blockIdx.y * BM;
    const int n0 = blockIdx.x * BN;

    float acc[8][8] = {};

    for (int k0 = 0; k0 < K; k0 += BK) {
        #pragma unroll
        for (int i = 0; i < 2; ++i) {
            int idx = t + i * 256;
            int row = idx >> 2;
            int c4  = (idx & 3) * 4;
            float4 av = *(const float4*)(A + (size_t)(m0 + row) * lda + k0 + c4);
            As[row][c4 + 0] = av.x; As[row][c4 + 1] = av.y;
            As[row][c4 + 2] = av.z; As[row][c4 + 3] = av.w;
            float4 bv = *(const float4*)(B + (size_t)(n0 + row) * ldb + k0 + c4);
            Bs[row][c4 + 0] = bv.x; Bs[row][c4 + 1] = bv.y;
            Bs[row][c4 + 2] = bv.z; Bs[row][c4 + 3] = bv.w;
        }
        __syncthreads();

        #pragma unroll
        for (int kk = 0; kk < BK; ++kk) {
            float a[8], b[8];
            #pragma unroll
            for (int i = 0; i < 8; ++i) a[i] = As[ty + 16 * i][kk];
            #pragma unroll
            for (int j = 0; j < 8; ++j) b[j] = Bs[tx + 16 * j][kk];
            #pragma unroll
            for (int i = 0; i < 8; ++i)
                #pragma unroll
                for (int j = 0; j < 8; ++j)
                    acc[i][j] += a[i] * b[j];
        }
        __syncthreads();
    }

    #pragma unroll
    for (int i = 0; i < 8; ++i)
        #pragma unroll
        for (int j = 0; j < 8; ++j)
            C[(size_t)(m0 + ty + 16 * i) * ldc + n0 + tx + 16 * j] = acc[i][j];
}

// ---------------------------------------------------------------------------
// In-place cos-scale + axial RoPE on q and k (unchanged).
// ---------------------------------------------------------------------------
__global__ __launch_bounds__(256) void transform_qk(
    float* __restrict__ qkv, const float* __restrict__ pos,
    const float* __restrict__ scale, const float* __restrict__ freqs)
{
    const int w    = threadIdx.x >> 6;
    const int lane = threadIdx.x & 63;
    const int rid  = blockIdx.x * 4 + w;
    const int l    = rid >> 4;
    const int h    = rid & 15;

    float* qp = qkv + (size_t)l * QKVN + h * DHEAD;
    float* kp = qp + DMODEL;

    float q = qp[lane];
    float k = kp[lane];

    float sq = q * q, sk = k * k;
    #pragma unroll
    for (int o = 32; o > 0; o >>= 1) {
        sq += __shfl_xor(sq, o);
        sk += __shfl_xor(sk, o);
    }
    const float ss = sqrtf(fabsf(scale[h]) + 1e-8f);
    q *= ss * rsqrtf(sq + 1e-8f);
    k *= ss * rsqrtf(sk + 1e-8f);

    const int   j  = lane & 31;
    const float p  = pos[l * 2 + (j < 16 ? 1 : 0)];
    const float fj = (j < 16) ? freqs[256 + h * 16 + j] : freqs[h * 16 + (j - 16)];
    const float th = (p * 2.0f - 1.0f) * fj;
    const float cs = cosf(th), sn = sinf(th);

    const float qo = __shfl_xor(q, 32);
    const float ko = __shfl_xor(k, 32);
    const float qr = (lane < 32) ? q * cs - qo * sn : q * cs + qo * sn;
    const float kr = (lane < 32) ? k * cs - ko * sn : k * cs + ko * sn;

    qp[lane] = qr;
    kp[lane] = kr;
}

// ---------------------------------------------------------------------------
// Stage one 64-row KV tile: K bf16 [kv][d] swizzled, V^T bf16 [d][kv] swizzled.
// ---------------------------------------------------------------------------
__device__ __forceinline__ void stage_kv(
    const float* __restrict__ qkv, short* Kl, short* VTl,
    int k0, int kcol, int vcol, int t)
{
    const int kv = t >> 2;
    const float* krow = qkv + (size_t)(k0 + kv) * QKVN + kcol;
    const float* vrow = qkv + (size_t)(k0 + kv) * QKVN + vcol;
    #pragma unroll
    for (int i = 0; i < 2; ++i) {
        const int o = (t & 3) + 4 * i;
        float4 a = *(const float4*)(krow + o * 8);
        float4 b = *(const float4*)(krow + o * 8 + 4);
        bf16x8 kb;
        kb[0] = f2bf(a.x); kb[1] = f2bf(a.y); kb[2] = f2bf(a.z); kb[3] = f2bf(a.w);
        kb[4] = f2bf(b.x); kb[5] = f2bf(b.y); kb[6] = f2bf(b.z); kb[7] = f2bf(b.w);
        *(bf16x8*)((char*)Kl + kv * 128 + ((o * 16) ^ swz(kv))) = kb;

        float4 c4 = *(const float4*)(vrow + o * 8);
        float4 d4 = *(const float4*)(vrow + o * 8 + 4);
        float vv[8] = {c4.x, c4.y, c4.z, c4.w, d4.x, d4.y, d4.z, d4.w};
        #pragma unroll
        for (int j = 0; j < 8; ++j) {
            const int d = o * 8 + j;
            *(short*)((char*)VTl + d * 128 + ((kv * 2) ^ swz(d))) = f2bf(vv[j]);
        }
    }
}

// ---------------------------------------------------------------------------
// MFMA flash attention over pokes (causal). Block = (head, 64 q-rows).
// ---------------------------------------------------------------------------
__global__ __launch_bounds__(256) void attn_pokes_mfma(float* __restrict__ qkv)
{
    __shared__ short Kl[64 * 64];
    __shared__ short VTl[64 * 64];

    const int h  = blockIdx.y;
    const int qt = gridDim.x - 1 - blockIdx.x;     // heavy blocks first
    const int q0 = qt * 64;
    const int t  = threadIdx.x;
    const int lane = t & 63, w = t >> 6;
    const int c = lane & 15, g = lane >> 4;
    const int qcol = h * DHEAD, kcol = DMODEL + h * DHEAD, vcol = 2 * DMODEL + h * DHEAD;
    const int qg = q0 + w * 16 + c;

    bf16x8 qf[2];
    {
        const float* qrow = qkv + (size_t)qg * QKVN + qcol + g * 8;
        #pragma unroll
        for (int kc = 0; kc < 2; ++kc) {
            float4 a = *(const float4*)(qrow + kc * 32);
            float4 b = *(const float4*)(qrow + kc * 32 + 4);
            bf16x8 v;
            v[0] = f2bf(a.x); v[1] = f2bf(a.y); v[2] = f2bf(a.z); v[3] = f2bf(a.w);
            v[4] = f2bf(b.x); v[5] = f2bf(b.y); v[6] = f2bf(b.z); v[7] = f2bf(b.w);
            qf[kc] = v;
        }
    }

    float m = -INFINITY, l = 0.0f;
    f32x4 acc[4] = {};

    for (int kt = 0; kt <= qt; ++kt) {
        const int k0 = kt * 64;
        __syncthreads();
        stage_kv(qkv, Kl, VTl, k0, kcol, vcol, t);
        __syncthreads();

        f32x4 st[4];
        #pragma unroll
        for (int mt = 0; mt < 4; ++mt) {
            const int kvr = mt * 16 + c;
            bf16x8 ka = *(const bf16x8*)((const char*)Kl + kvr * 128 + ((g * 16) ^ swz(kvr)));
            bf16x8 kb = *(const bf16x8*)((const char*)Kl + kvr * 128 + ((64 + g * 16) ^ swz(kvr)));
            f32x4 z = {0.f, 0.f, 0.f, 0.f};
            z = __builtin_amdgcn_mfma_f32_16x16x32_bf16(ka, qf[0], z, 0, 0, 0);
            st[mt] = __builtin_amdgcn_mfma_f32_16x16x32_bf16(kb, qf[1], z, 0, 0, 0);
        }

        if (kt == qt) {
            #pragma unroll
            for (int mt = 0; mt < 4; ++mt)
                #pragma unroll
                for (int r = 0; r < 4; ++r)
                    if (k0 + mt * 16 + g * 4 + r > qg) st[mt][r] = -INFINITY;
        }

        float tmax = -INFINITY;
        #pragma unroll
        for (int mt = 0; mt < 4; ++mt)
            #pragma unroll
            for (int r = 0; r < 4; ++r) tmax = fmaxf(tmax, st[mt][r]);
        tmax = fmaxf(tmax, __shfl_xor(tmax, 16));
        tmax = fmaxf(tmax, __shfl_xor(tmax, 32));
        const float mnew = fmaxf(m, tmax);
        const float pfac = __expf(m - mnew);
        float p[4][4];
        float rs = 0.0f;
        #pragma unroll
        for (int mt = 0; mt < 4; ++mt)
            #pragma unroll
            for (int r = 0; r < 4; ++r) {
                float e = __expf(st[mt][r] - mnew);
                p[mt][r] = e;
                rs += e;
            }
        rs += __shfl_xor(rs, 16);
        rs += __shfl_xor(rs, 32);
        l = l * pfac + rs;
        m = mnew;
        #pragma unroll
        for (int dt = 0; dt < 4; ++dt)
            #pragma unroll
            for (int r = 0; r < 4; ++r) acc[dt][r] *= pfac;

        #pragma unroll
        for (int kc = 0; kc < 2; ++kc) {
            bf16x8 pb;
            #pragma unroll
            for (int j = 0; j < 8; ++j) {
                const int src = c + 16 * (2 * (g & 1) + (j >> 2));
                const float v0 = __shfl(p[kc * 2    ][j & 3], src);
                const float v1 = __shfl(p[kc * 2 + 1][j & 3], src);
                pb[j] = f2bf((g >> 1) ? v1 : v0);
            }
            #pragma unroll
            for (int dt = 0; dt < 4; ++dt) {
                const int dr = dt * 16 + c;
                bf16x8 vf = *(const bf16x8*)((const char*)VTl + dr * 128 + ((kc * 64 + g * 16) ^ swz(dr)));
                acc[dt] = __builtin_amdgcn_mfma_f32_16x16x32_bf16(vf, pb, acc[dt], 0, 0, 0);
            }
        }
    }

    const float inv = 1.0f / l;
    float* orow = qkv + (size_t)qg * QKVN + qcol;
    #pragma unroll
    for (int dt = 0; dt < 4; ++dt)
        #pragma unroll
        for (int r = 0; r < 4; ++r)
            orow[dt * 16 + g * 4 + r] = acc[dt][r] * inv;
}

// ---------------------------------------------------------------------------
// MFMA query attention: 64 q-rows/block attend to all 3072 pokes + self.
// ---------------------------------------------------------------------------
__global__ __launch_bounds__(256) void attn_query_mfma(float* __restrict__ qkv)
{
    __shared__ short Kl[64 * 64];
    __shared__ short VTl[64 * 64];

    const int h  = blockIdx.y;
    const int q0 = SPOKES + blockIdx.x * 64;
    const int t  = threadIdx.x;
    const int lane = t & 63, w = t >> 6;
    const int c = lane & 15, g = lane >> 4;
    const int qcol = h * DHEAD, kcol = DMODEL + h * DHEAD, vcol = 2 * DMODEL + h * DHEAD;
    const int qg = q0 + w * 16 + c;

    bf16x8 qf[2];
    float  qf32[2][8];
    {
        const float* qrow = qkv + (size_t)qg * QKVN + qcol + g * 8;
        #pragma unroll
        for (int kc = 0; kc < 2; ++kc) {
            float4 a = *(const float4*)(qrow + kc * 32);
            float4 b = *(const float4*)(qrow + kc * 32 + 4);
            qf32[kc][0] = a.x; qf32[kc][1] = a.y; qf32[kc][2] = a.z; qf32[kc][3] = a.w;
            qf32[kc][4] = b.x; qf32[kc][5] = b.y; qf32[kc][6] = b.z; qf32[kc][7] = b.w;
            bf16x8 v;
            #pragma unroll
            for (int j = 0; j < 8; ++j) v[j] = f2bf(qf32[kc][j]);
            qf[kc] = v;
        }
    }

    float sself = 0.0f;
    {
        const float* krow = qkv + (size_t)qg * QKVN + kcol + g * 8;
        #pragma unroll
        for (int kc = 0; kc < 2; ++kc)
            #pragma unroll
            for (int j = 0; j < 8; ++j) sself += qf32[kc][j] * krow[kc * 32 + j];
        sself += __shfl_xor(sself, 16);
        sself += __shfl_xor(sself, 32);
    }
    float vq[4][4];
    {
        const float* vrow = qkv + (size_t)qg * QKVN + vcol;
        #pragma unroll
        for (int dt = 0; dt < 4; ++dt)
            #pragma unroll
            for (int r = 0; r < 4; ++r) vq[dt][r] = vrow[dt * 16 + g * 4 + r];
    }

    float m = -INFINITY, l = 0.0f;
    f32x4 acc[4] = {};

    for (int kt = 0; kt < SPOKES / 64; ++kt) {
        const int k0 = kt * 64;
        __syncthreads();
        stage_kv(qkv, Kl, VTl, k0, kcol, vcol, t);
        __syncthreads();

        f32x4 st[4];
        #pragma unroll
        for (int mt = 0; mt < 4; ++mt) {
            const int kvr = mt * 16 + c;
            bf16x8 ka = *(const bf16x8*)((const char*)Kl + kvr * 128 + ((g * 16) ^ swz(kvr)));
            bf16x8 kb = *(const bf16x8*)((const char*)Kl + kvr * 128 + ((64 + g * 16) ^ swz(kvr)));
            f32x4 z = {0.f, 0.f, 0.f, 0.f};
            z = __builtin_amdgcn_mfma_f32_16x16x32_bf16(ka, qf[0], z, 0, 0, 0);
            st[mt] = __builtin_amdgcn_mfma_f32_16x16x32_bf16(kb, qf[1], z, 0, 0, 0);
        }

        float tmax = -INFINITY;
        #pragma unroll
        for (int mt = 0; mt < 4; ++mt)
            #pragma unroll
            for (int r = 0; r < 4; ++r) tmax = fmaxf(tmax, st[mt][r]);
        tmax = fmaxf(tmax, __shfl_xor(tmax, 16));
        tmax = fmaxf(tmax, __shfl_xor(tmax, 32));
        const float mnew = fmaxf(m, tmax);
        const float pfac = __expf(m - mnew);
        float p[4][4];
        float rs = 0.0f;
        #pragma unroll
        for (int mt = 0; mt < 4; ++mt)
            #pragma unroll
            for (int r = 0; r < 4; ++r) {
                float e = __expf(st[mt][r] - mnew);
                p[mt][r] = e;
                rs += e;
            }
        rs += __shfl_xor(rs, 16);
        rs += __shfl_xor(rs, 32);
        l = l * pfac + rs;
        m = mnew;
        #pragma unroll
        for (int dt = 0; dt < 4; ++dt)
            #pragma unroll
            for (int r = 0; r < 4; ++r) acc[dt][r] *= pfac;

        #pragma unroll
        for (int kc = 0; kc < 2; ++kc) {
            bf16x8 pb;
            #pragma unroll
            for (int j = 0; j < 8; ++j) {
                const int src = c + 16 * (2 * (g & 1) + (j >> 2));
                const float v0 = __shfl(p[kc * 2    ][j & 3], src);
                const float v1 = __shfl(p[kc * 2 + 1][j & 3], src);
                pb[j] = f2bf((g >> 1) ? v1 : v0);
            }
            #pragma unroll
            for (int dt = 0; dt < 4; ++dt) {
                const int dr = dt * 16 + c;
                bf16x8 vf = *(const bf16x8*)((const char*)VTl + dr * 128 + ((kc * 64 + g * 16) ^ swz(dr)));
                acc[dt] = __builtin_amdgcn_mfma_f32_16x16x32_bf16(vf, pb, acc[dt], 0, 0, 0);
            }
        }
    }

    const float mnew = fmaxf(m, sself);
    const float pf   = __expf(m - mnew);
    const float ps   = __expf(sself - mnew);
    const float linv = 1.0f / (l * pf + ps);
    float* orow = qkv + (size_t)qg * QKVN + qcol;
    #pragma unroll
    for (int dt = 0; dt < 4; ++dt)
        #pragma unroll
        for (int r = 0; r < 4; ++r)
            orow[dt * 16 + g * 4 + r] = (acc[dt][r] * pf + ps * vq[dt][r]) * linv;
}

// ---------------------------------------------------------------------------
extern "C" void kernel_launch(void* const* d_in, const int* in_sizes, int n_in,
                              void* d_out, int out_size, void* d_ws, size_t ws_size,
                              hipStream_t stream)
{
    const float* x      = (const float*)d_in[0];
    const float* pos    = (const float*)d_in[1];
    const float* qkv_w  = (const float*)d_in[2];
    const float* out_w  = (const float*)d_in[3];
    const float* scale  = (const float*)d_in[4];
    const float* freqs  = (const float*)d_in[5];
    float*       out    = (float*)d_out;
    float*       qkv    = (float*)d_ws;           // SEQL x 3072 f32 = 48 MB

    const dim3 blk(256);

    gemm_abt<<<dim3(QKVN / 128, SEQL / 128), blk, 0, stream>>>(
        x, qkv_w, qkv, SEQL, QKVN, DMODEL, DMODEL, DMODEL, QKVN);

    transform_qk<<<dim3(SEQL * NH / 4), blk, 0, stream>>>(qkv, pos, scale, freqs);

    attn_pokes_mfma<<<dim3(SPOKES / 64, NH), blk, 0, stream>>>(qkv);

    attn_query_mfma<<<dim3(NQUERY / 64, NH), blk, 0, stream>>>(qkv);

    gemm_abt<<<dim3(DMODEL / 128, SEQL / 128), blk, 0, stream>>>(
        qkv, out_w, out, SEQL, DMODEL, DMODEL, QKVN, DMODEL, DMODEL);
}

// Round 3
// 329.928 us; speedup vs baseline: 6.5646x; 2.4499x over previous
//
#include <hip/hip_runtime.h>
#include <math.h>

#define SEQL   4096
#define DMODEL 1024
#define NH     16
#define DHEAD  64
#define SPOKES 3072
#define NQUERY (SEQL - SPOKES)     // 1024
#define QKVN   (3 * DMODEL)        // 3072

typedef short bf16x8 __attribute__((ext_vector_type(8)));
typedef float f32x4  __attribute__((ext_vector_type(4)));

__device__ __forceinline__ short f2bf(float f) {
    unsigned u = __builtin_bit_cast(unsigned, f);
    u += 0x7fffu + ((u >> 16) & 1u);     // RNE
    return (short)(u >> 16);
}
__device__ __forceinline__ float bf2f(short s) {
    unsigned u = ((unsigned)(unsigned short)s) << 16;
    return __builtin_bit_cast(float, u);
}
// XOR swizzle on bits 4..6 of the byte address, keyed by LDS row (attention tiles).
__device__ __forceinline__ int swz(int row) { return ((row & 7) ^ (row >> 3)) << 4; }

// async global->LDS, 16B per lane; LDS dest = wave-uniform base + lane*16
__device__ __forceinline__ void gload_lds16(const void* g, void* l) {
    __builtin_amdgcn_global_load_lds(
        (const __attribute__((address_space(1))) unsigned int*)g,
        (__attribute__((address_space(3))) unsigned int*)l,
        16, 0, 0);
}

// ---------------------------------------------------------------------------
// f32 -> bf16 conversion, 8 elems/thread
// ---------------------------------------------------------------------------
__global__ __launch_bounds__(256) void cvt_f32_bf16(
    const float* __restrict__ in, short* __restrict__ out, int n8)
{
    const int i = blockIdx.x * 256 + threadIdx.x;
    if (i >= n8) return;
    float4 a = ((const float4*)in)[i * 2];
    float4 b = ((const float4*)in)[i * 2 + 1];
    bf16x8 v;
    v[0] = f2bf(a.x); v[1] = f2bf(a.y); v[2] = f2bf(a.z); v[3] = f2bf(a.w);
    v[4] = f2bf(b.x); v[5] = f2bf(b.y); v[6] = f2bf(b.z); v[7] = f2bf(b.w);
    ((bf16x8*)out)[i] = v;
}

// ---------------------------------------------------------------------------
// bf16 MFMA GEMM: C[M][N] = A[M][K] * B[N][K]^T, A/B bf16 row-major (ld = K),
// C f32 or bf16. 128x128 tile, BK=64, 4 waves, global_load_lds staging,
// 2-barrier K-loop (m97 structure).
// ---------------------------------------------------------------------------
template<bool BF16OUT>
__global__ __launch_bounds__(256) void gemm_bf16(
    const short* __restrict__ A, const short* __restrict__ B, void* __restrict__ Cv,
    int K, int ldc)
{
    __shared__ short As[128 * 64];
    __shared__ short Bs[128 * 64];

    const int t = threadIdx.x;
    const int lane = t & 63, w = t >> 6;
    const int c = lane & 15, g = lane >> 4;
    const int wr = w >> 1, wc = w & 1;
    const int m0 = blockIdx.y * 128, n0 = blockIdx.x * 128;

    f32x4 acc[4][4] = {};

    for (int k0 = 0; k0 < K; k0 += 64) {
        __syncthreads();            // prior compute done before overwrite
        #pragma unroll
        for (int i = 0; i < 4; ++i) {
            const int chunk = (w * 4 + i) * 64 + lane;   // 0..1023
            const int row = chunk >> 3, cc = chunk & 7;
            gload_lds16(A + (size_t)(m0 + row) * K + k0 + cc * 8,
                        As + (size_t)(w * 4 + i) * 512);
            gload_lds16(B + (size_t)(n0 + row) * K + k0 + cc * 8,
                        Bs + (size_t)(w * 4 + i) * 512);
        }
        __syncthreads();            // drains vmcnt -> tiles visible

        #pragma unroll
        for (int kk = 0; kk < 2; ++kk) {
            bf16x8 af[4], bf[4];
            #pragma unroll
            for (int i = 0; i < 4; ++i)
                af[i] = *(const bf16x8*)(As + (wr * 64 + i * 16 + c) * 64 + kk * 32 + g * 8);
            #pragma unroll
            for (int j = 0; j < 4; ++j)
                bf[j] = *(const bf16x8*)(Bs + (wc * 64 + j * 16 + c) * 64 + kk * 32 + g * 8);
            #pragma unroll
            for (int i = 0; i < 4; ++i)
                #pragma unroll
                for (int j = 0; j < 4; ++j)
                    acc[i][j] = __builtin_amdgcn_mfma_f32_16x16x32_bf16(af[i], bf[j], acc[i][j], 0, 0, 0);
        }
    }

    #pragma unroll
    for (int i = 0; i < 4; ++i)
        #pragma unroll
        for (int r = 0; r < 4; ++r) {
            const int row = m0 + wr * 64 + i * 16 + g * 4 + r;
            #pragma unroll
            for (int j = 0; j < 4; ++j) {
                const int col = n0 + wc * 64 + j * 16 + c;
                const float v = acc[i][j][r];
                if (BF16OUT) ((short*)Cv)[(size_t)row * ldc + col] = f2bf(v);
                else         ((float*)Cv)[(size_t)row * ldc + col] = v;
            }
        }
}

// ---------------------------------------------------------------------------
// In-place cos-scale + axial RoPE on bf16 q and k.
// ---------------------------------------------------------------------------
__global__ __launch_bounds__(256) void transform_qk(
    short* __restrict__ qkv, const float* __restrict__ pos,
    const float* __restrict__ scale, const float* __restrict__ freqs)
{
    const int w    = threadIdx.x >> 6;
    const int lane = threadIdx.x & 63;
    const int rid  = blockIdx.x * 4 + w;
    const int l    = rid >> 4;
    const int h    = rid & 15;

    short* qp = qkv + (size_t)l * QKVN + h * DHEAD;
    short* kp = qp + DMODEL;

    float q = bf2f(qp[lane]);
    float k = bf2f(kp[lane]);

    float sq = q * q, sk = k * k;
    #pragma unroll
    for (int o = 32; o > 0; o >>= 1) {
        sq += __shfl_xor(sq, o);
        sk += __shfl_xor(sk, o);
    }
    const float ss = sqrtf(fabsf(scale[h]) + 1e-8f);
    q *= ss * rsqrtf(sq + 1e-8f);
    k *= ss * rsqrtf(sk + 1e-8f);

    const int   j  = lane & 31;
    const float p  = pos[l * 2 + (j < 16 ? 1 : 0)];
    const float fj = (j < 16) ? freqs[256 + h * 16 + j] : freqs[h * 16 + (j - 16)];
    const float th = (p * 2.0f - 1.0f) * fj;
    const float cs = cosf(th), sn = sinf(th);

    const float qo = __shfl_xor(q, 32);
    const float ko = __shfl_xor(k, 32);
    const float qr = (lane < 32) ? q * cs - qo * sn : q * cs + qo * sn;
    const float kr = (lane < 32) ? k * cs - ko * sn : k * cs + ko * sn;

    qp[lane] = f2bf(qr);
    kp[lane] = f2bf(kr);
}

// ---------------------------------------------------------------------------
// Stage one 64-row KV tile from bf16 qkv: K [kv][d] swizzled, V^T [d][kv] swz.
// ---------------------------------------------------------------------------
__device__ __forceinline__ void stage_kv(
    const short* __restrict__ qkv, short* Kl, short* VTl,
    int k0, int kcol, int vcol, int t)
{
    const int kv = t >> 2;
    const short* krow = qkv + (size_t)(k0 + kv) * QKVN + kcol;
    const short* vrow = qkv + (size_t)(k0 + kv) * QKVN + vcol;
    #pragma unroll
    for (int i = 0; i < 2; ++i) {
        const int o = (t & 3) + 4 * i;
        bf16x8 kb = *(const bf16x8*)(krow + o * 8);
        *(bf16x8*)((char*)Kl + kv * 128 + ((o * 16) ^ swz(kv))) = kb;
        bf16x8 vb = *(const bf16x8*)(vrow + o * 8);
        #pragma unroll
        for (int j = 0; j < 8; ++j) {
            const int d = o * 8 + j;
            *(short*)((char*)VTl + d * 128 + ((kv * 2) ^ swz(d))) = vb[j];
        }
    }
}

// ---------------------------------------------------------------------------
// MFMA flash attention over pokes (causal). Block = (head, 64 q-rows).
// Output -> compact bf16 attn buffer [SEQL][DMODEL].
// ---------------------------------------------------------------------------
__global__ __launch_bounds__(256) void attn_pokes_mfma(
    const short* __restrict__ qkv, short* __restrict__ attn)
{
    __shared__ short Kl[64 * 64];
    __shared__ short VTl[64 * 64];

    const int h  = blockIdx.y;
    const int qt = gridDim.x - 1 - blockIdx.x;     // heavy blocks first
    const int q0 = qt * 64;
    const int t  = threadIdx.x;
    const int lane = t & 63, w = t >> 6;
    const int c = lane & 15, g = lane >> 4;
    const int qcol = h * DHEAD, kcol = DMODEL + h * DHEAD, vcol = 2 * DMODEL + h * DHEAD;
    const int qg = q0 + w * 16 + c;

    bf16x8 qf[2];
    {
        const short* qrow = qkv + (size_t)qg * QKVN + qcol;
        qf[0] = *(const bf16x8*)(qrow + g * 8);
        qf[1] = *(const bf16x8*)(qrow + 32 + g * 8);
    }

    float m = -INFINITY, l = 0.0f;
    f32x4 acc[4] = {};

    for (int kt = 0; kt <= qt; ++kt) {
        const int k0 = kt * 64;
        __syncthreads();
        stage_kv(qkv, Kl, VTl, k0, kcol, vcol, t);
        __syncthreads();

        f32x4 st[4];
        #pragma unroll
        for (int mt = 0; mt < 4; ++mt) {
            const int kvr = mt * 16 + c;
            bf16x8 ka = *(const bf16x8*)((const char*)Kl + kvr * 128 + ((g * 16) ^ swz(kvr)));
            bf16x8 kb = *(const bf16x8*)((const char*)Kl + kvr * 128 + ((64 + g * 16) ^ swz(kvr)));
            f32x4 z = {0.f, 0.f, 0.f, 0.f};
            z = __builtin_amdgcn_mfma_f32_16x16x32_bf16(ka, qf[0], z, 0, 0, 0);
            st[mt] = __builtin_amdgcn_mfma_f32_16x16x32_bf16(kb, qf[1], z, 0, 0, 0);
        }

        if (kt == qt) {
            #pragma unroll
            for (int mt = 0; mt < 4; ++mt)
                #pragma unroll
                for (int r = 0; r < 4; ++r)
                    if (k0 + mt * 16 + g * 4 + r > qg) st[mt][r] = -INFINITY;
        }

        float tmax = -INFINITY;
        #pragma unroll
        for (int mt = 0; mt < 4; ++mt)
            #pragma unroll
            for (int r = 0; r < 4; ++r) tmax = fmaxf(tmax, st[mt][r]);
        tmax = fmaxf(tmax, __shfl_xor(tmax, 16));
        tmax = fmaxf(tmax, __shfl_xor(tmax, 32));
        const float mnew = fmaxf(m, tmax);
        const float pfac = __expf(m - mnew);
        float p[4][4];
        float rs = 0.0f;
        #pragma unroll
        for (int mt = 0; mt < 4; ++mt)
            #pragma unroll
            for (int r = 0; r < 4; ++r) {
                float e = __expf(st[mt][r] - mnew);
                p[mt][r] = e;
                rs += e;
            }
        rs += __shfl_xor(rs, 16);
        rs += __shfl_xor(rs, 32);
        l = l * pfac + rs;
        m = mnew;
        #pragma unroll
        for (int dt = 0; dt < 4; ++dt)
            #pragma unroll
            for (int r = 0; r < 4; ++r) acc[dt][r] *= pfac;

        #pragma unroll
        for (int kc = 0; kc < 2; ++kc) {
            bf16x8 pb;
            #pragma unroll
            for (int j = 0; j < 8; ++j) {
                const int src = c + 16 * (2 * (g & 1) + (j >> 2));
                const float v0 = __shfl(p[kc * 2    ][j & 3], src);
                const float v1 = __shfl(p[kc * 2 + 1][j & 3], src);
                pb[j] = f2bf((g >> 1) ? v1 : v0);
            }
            #pragma unroll
            for (int dt = 0; dt < 4; ++dt) {
                const int dr = dt * 16 + c;
                bf16x8 vf = *(const bf16x8*)((const char*)VTl + dr * 128 + ((kc * 64 + g * 16) ^ swz(dr)));
                acc[dt] = __builtin_amdgcn_mfma_f32_16x16x32_bf16(vf, pb, acc[dt], 0, 0, 0);
            }
        }
    }

    const float inv = 1.0f / l;
    short* orow = attn + (size_t)qg * DMODEL + qcol;
    #pragma unroll
    for (int dt = 0; dt < 4; ++dt)
        #pragma unroll
        for (int r = 0; r < 4; ++r)
            orow[dt * 16 + g * 4 + r] = f2bf(acc[dt][r] * inv);
}

// ---------------------------------------------------------------------------
// MFMA query attention: 64 q-rows/block attend to all 3072 pokes + self.
// ---------------------------------------------------------------------------
__global__ __launch_bounds__(256) void attn_query_mfma(
    const short* __restrict__ qkv, short* __restrict__ attn)
{
    __shared__ short Kl[64 * 64];
    __shared__ short VTl[64 * 64];

    const int h  = blockIdx.y;
    const int q0 = SPOKES + blockIdx.x * 64;
    const int t  = threadIdx.x;
    const int lane = t & 63, w = t >> 6;
    const int c = lane & 15, g = lane >> 4;
    const int qcol = h * DHEAD, kcol = DMODEL + h * DHEAD, vcol = 2 * DMODEL + h * DHEAD;
    const int qg = q0 + w * 16 + c;

    bf16x8 qf[2];
    {
        const short* qrow = qkv + (size_t)qg * QKVN + qcol;
        qf[0] = *(const bf16x8*)(qrow + g * 8);
        qf[1] = *(const bf16x8*)(qrow + 32 + g * 8);
    }

    // self score (f32 accumulate over bf16 q,k) + self V fragment
    float sself = 0.0f;
    {
        const short* krow = qkv + (size_t)qg * QKVN + kcol;
        #pragma unroll
        for (int kc = 0; kc < 2; ++kc)
            #pragma unroll
            for (int j = 0; j < 8; ++j)
                sself += bf2f(qf[kc][j]) * bf2f(krow[kc * 32 + g * 8 + j]);
        sself += __shfl_xor(sself, 16);
        sself += __shfl_xor(sself, 32);
    }
    float vq[4][4];
    {
        const short* vrow = qkv + (size_t)qg * QKVN + vcol;
        #pragma unroll
        for (int dt = 0; dt < 4; ++dt)
            #pragma unroll
            for (int r = 0; r < 4; ++r) vq[dt][r] = bf2f(vrow[dt * 16 + g * 4 + r]);
    }

    float m = -INFINITY, l = 0.0f;
    f32x4 acc[4] = {};

    for (int kt = 0; kt < SPOKES / 64; ++kt) {
        const int k0 = kt * 64;
        __syncthreads();
        stage_kv(qkv, Kl, VTl, k0, kcol, vcol, t);
        __syncthreads();

        f32x4 st[4];
        #pragma unroll
        for (int mt = 0; mt < 4; ++mt) {
            const int kvr = mt * 16 + c;
            bf16x8 ka = *(const bf16x8*)((const char*)Kl + kvr * 128 + ((g * 16) ^ swz(kvr)));
            bf16x8 kb = *(const bf16x8*)((const char*)Kl + kvr * 128 + ((64 + g * 16) ^ swz(kvr)));
            f32x4 z = {0.f, 0.f, 0.f, 0.f};
            z = __builtin_amdgcn_mfma_f32_16x16x32_bf16(ka, qf[0], z, 0, 0, 0);
            st[mt] = __builtin_amdgcn_mfma_f32_16x16x32_bf16(kb, qf[1], z, 0, 0, 0);
        }

        float tmax = -INFINITY;
        #pragma unroll
        for (int mt = 0; mt < 4; ++mt)
            #pragma unroll
            for (int r = 0; r < 4; ++r) tmax = fmaxf(tmax, st[mt][r]);
        tmax = fmaxf(tmax, __shfl_xor(tmax, 16));
        tmax = fmaxf(tmax, __shfl_xor(tmax, 32));
        const float mnew = fmaxf(m, tmax);
        const float pfac = __expf(m - mnew);
        float p[4][4];
        float rs = 0.0f;
        #pragma unroll
        for (int mt = 0; mt < 4; ++mt)
            #pragma unroll
            for (int r = 0; r < 4; ++r) {
                float e = __expf(st[mt][r] - mnew);
                p[mt][r] = e;
                rs += e;
            }
        rs += __shfl_xor(rs, 16);
        rs += __shfl_xor(rs, 32);
        l = l * pfac + rs;
        m = mnew;
        #pragma unroll
        for (int dt = 0; dt < 4; ++dt)
            #pragma unroll
            for (int r = 0; r < 4; ++r) acc[dt][r] *= pfac;

        #pragma unroll
        for (int kc = 0; kc < 2; ++kc) {
            bf16x8 pb;
            #pragma unroll
            for (int j = 0; j < 8; ++j) {
                const int src = c + 16 * (2 * (g & 1) + (j >> 2));
                const float v0 = __shfl(p[kc * 2    ][j & 3], src);
                const float v1 = __shfl(p[kc * 2 + 1][j & 3], src);
                pb[j] = f2bf((g >> 1) ? v1 : v0);
            }
            #pragma unroll
            for (int dt = 0; dt < 4; ++dt) {
                const int dr = dt * 16 + c;
                bf16x8 vf = *(const bf16x8*)((const char*)VTl + dr * 128 + ((kc * 64 + g * 16) ^ swz(dr)));
                acc[dt] = __builtin_amdgcn_mfma_f32_16x16x32_bf16(vf, pb, acc[dt], 0, 0, 0);
            }
        }
    }

    const float mnew = fmaxf(m, sself);
    const float pf   = __expf(m - mnew);
    const float ps   = __expf(sself - mnew);
    const float linv = 1.0f / (l * pf + ps);
    short* orow = attn + (size_t)qg * DMODEL + qcol;
    #pragma unroll
    for (int dt = 0; dt < 4; ++dt)
        #pragma unroll
        for (int r = 0; r < 4; ++r)
            orow[dt * 16 + g * 4 + r] = f2bf((acc[dt][r] * pf + ps * vq[dt][r]) * linv);
}

// ---------------------------------------------------------------------------
extern "C" void kernel_launch(void* const* d_in, const int* in_sizes, int n_in,
                              void* d_out, int out_size, void* d_ws, size_t ws_size,
                              hipStream_t stream)
{
    const float* x      = (const float*)d_in[0];
    const float* pos    = (const float*)d_in[1];
    const float* qkv_w  = (const float*)d_in[2];
    const float* out_w  = (const float*)d_in[3];
    const float* scale  = (const float*)d_in[4];
    const float* freqs  = (const float*)d_in[5];
    float*       out    = (float*)d_out;

    char* ws = (char*)d_ws;
    short* qkv_bf  = (short*)(ws);                                   // 24 MB
    short* x_bf    = (short*)(ws + (size_t)24 * 1024 * 1024);        //  8 MB
    short* wqkv_bf = (short*)(ws + (size_t)32 * 1024 * 1024);        //  6 MB
    short* wout_bf = (short*)(ws + (size_t)38 * 1024 * 1024);        //  2 MB
    short* attn_bf = (short*)(ws + (size_t)40 * 1024 * 1024);        //  8 MB

    const dim3 blk(256);

    cvt_f32_bf16<<<dim3(SEQL * DMODEL / 8 / 256), blk, 0, stream>>>(x, x_bf, SEQL * DMODEL / 8);
    cvt_f32_bf16<<<dim3(QKVN * DMODEL / 8 / 256), blk, 0, stream>>>(qkv_w, wqkv_bf, QKVN * DMODEL / 8);
    cvt_f32_bf16<<<dim3(DMODEL * DMODEL / 8 / 256), blk, 0, stream>>>(out_w, wout_bf, DMODEL * DMODEL / 8);

    // 1) qkv = x @ qkv_w^T  (bf16 in, bf16 out)
    gemm_bf16<true><<<dim3(QKVN / 128, SEQL / 128), blk, 0, stream>>>(
        x_bf, wqkv_bf, qkv_bf, DMODEL, QKVN);

    // 2) cos-scale + axial rope on q,k (in place, bf16)
    transform_qk<<<dim3(SEQL * NH / 4), blk, 0, stream>>>(qkv_bf, pos, scale, freqs);

    // 3) causal attention over pokes -> attn_bf rows [0, SPOKES)
    attn_pokes_mfma<<<dim3(SPOKES / 64, NH), blk, 0, stream>>>(qkv_bf, attn_bf);

    // 4) query attention -> attn_bf rows [SPOKES, SEQL)
    attn_query_mfma<<<dim3(NQUERY / 64, NH), blk, 0, stream>>>(qkv_bf, attn_bf);

    // 5) out = attn @ out_w^T  (bf16 in, f32 out)
    gemm_bf16<false><<<dim3(DMODEL / 128, SEQL / 128), blk, 0, stream>>>(
        attn_bf, wout_bf, out, DMODEL, DMODEL);
}

// Round 4
// 262.929 us; speedup vs baseline: 8.2374x; 1.2548x over previous
//
#include <hip/hip_runtime.h>
#include <math.h>

#define SEQL   4096
#define DMODEL 1024
#define NH     16
#define DHEAD  64
#define SPOKES 3072
#define NQUERY (SEQL - SPOKES)     // 1024
#define QKVN   (3 * DMODEL)        // 3072
#define NSPLIT 4                   // kv-splits for query attention
#define QTILES (SPOKES / 64 / NSPLIT)   // 12 tiles per split

typedef short bf16x8 __attribute__((ext_vector_type(8)));
typedef short bf16x4 __attribute__((ext_vector_type(4)));
typedef float f32x4  __attribute__((ext_vector_type(4)));

__device__ __forceinline__ short f2bf(float f) {
    unsigned u = __builtin_bit_cast(unsigned, f);
    u += 0x7fffu + ((u >> 16) & 1u);     // RNE
    return (short)(u >> 16);
}
__device__ __forceinline__ float bf2f(short s) {
    unsigned u = ((unsigned)(unsigned short)s) << 16;
    return __builtin_bit_cast(float, u);
}
// XOR swizzle on byte bits 4..6, keyed by LDS row (rows are 128B).
__device__ __forceinline__ int swz(int row) { return ((row & 7) ^ (row >> 3)) << 4; }

// async global->LDS, 16B per lane; LDS dest = wave-uniform base + lane*16
__device__ __forceinline__ void gload_lds16(const void* g, void* l) {
    __builtin_amdgcn_global_load_lds(
        (const __attribute__((address_space(1))) unsigned int*)g,
        (__attribute__((address_space(3))) unsigned int*)l,
        16, 0, 0);
}

// ---------------------------------------------------------------------------
// f32 -> bf16 conversion, 8 elems/thread
// ---------------------------------------------------------------------------
__global__ __launch_bounds__(256) void cvt_f32_bf16(
    const float* __restrict__ in, short* __restrict__ out, int n8)
{
    const int i = blockIdx.x * 256 + threadIdx.x;
    if (i >= n8) return;
    float4 a = ((const float4*)in)[i * 2];
    float4 b = ((const float4*)in)[i * 2 + 1];
    bf16x8 v;
    v[0] = f2bf(a.x); v[1] = f2bf(a.y); v[2] = f2bf(a.z); v[3] = f2bf(a.w);
    v[4] = f2bf(b.x); v[5] = f2bf(b.y); v[6] = f2bf(b.z); v[7] = f2bf(b.w);
    ((bf16x8*)out)[i] = v;
}

// ---------------------------------------------------------------------------
// bf16 MFMA GEMM (unchanged from round 3): C = A * B^T, 128x128 tile, BK=64.
// ---------------------------------------------------------------------------
template<bool BF16OUT>
__global__ __launch_bounds__(256) void gemm_bf16(
    const short* __restrict__ A, const short* __restrict__ B, void* __restrict__ Cv,
    int K, int ldc)
{
    __shared__ short As[128 * 64];
    __shared__ short Bs[128 * 64];

    const int t = threadIdx.x;
    const int lane = t & 63, w = t >> 6;
    const int c = lane & 15, g = lane >> 4;
    const int wr = w >> 1, wc = w & 1;
    const int m0 = blockIdx.y * 128, n0 = blockIdx.x * 128;

    f32x4 acc[4][4] = {};

    for (int k0 = 0; k0 < K; k0 += 64) {
        __syncthreads();
        #pragma unroll
        for (int i = 0; i < 4; ++i) {
            const int chunk = (w * 4 + i) * 64 + lane;
            const int row = chunk >> 3, cc = chunk & 7;
            gload_lds16(A + (size_t)(m0 + row) * K + k0 + cc * 8,
                        As + (size_t)(w * 4 + i) * 512);
            gload_lds16(B + (size_t)(n0 + row) * K + k0 + cc * 8,
                        Bs + (size_t)(w * 4 + i) * 512);
        }
        __syncthreads();

        #pragma unroll
        for (int kk = 0; kk < 2; ++kk) {
            bf16x8 af[4], bf[4];
            #pragma unroll
            for (int i = 0; i < 4; ++i)
                af[i] = *(const bf16x8*)(As + (wr * 64 + i * 16 + c) * 64 + kk * 32 + g * 8);
            #pragma unroll
            for (int j = 0; j < 4; ++j)
                bf[j] = *(const bf16x8*)(Bs + (wc * 64 + j * 16 + c) * 64 + kk * 32 + g * 8);
            #pragma unroll
            for (int i = 0; i < 4; ++i)
                #pragma unroll
                for (int j = 0; j < 4; ++j)
                    acc[i][j] = __builtin_amdgcn_mfma_f32_16x16x32_bf16(af[i], bf[j], acc[i][j], 0, 0, 0);
        }
    }

    #pragma unroll
    for (int i = 0; i < 4; ++i)
        #pragma unroll
        for (int r = 0; r < 4; ++r) {
            const int row = m0 + wr * 64 + i * 16 + g * 4 + r;
            #pragma unroll
            for (int j = 0; j < 4; ++j) {
                const int col = n0 + wc * 64 + j * 16 + c;
                const float v = acc[i][j][r];
                if (BF16OUT) ((short*)Cv)[(size_t)row * ldc + col] = f2bf(v);
                else         ((float*)Cv)[(size_t)row * ldc + col] = v;
            }
        }
}

// ---------------------------------------------------------------------------
// In-place cos-scale + axial RoPE on bf16 q and k (unchanged).
// ---------------------------------------------------------------------------
__global__ __launch_bounds__(256) void transform_qk(
    short* __restrict__ qkv, const float* __restrict__ pos,
    const float* __restrict__ scale, const float* __restrict__ freqs)
{
    const int w    = threadIdx.x >> 6;
    const int lane = threadIdx.x & 63;
    const int rid  = blockIdx.x * 4 + w;
    const int l    = rid >> 4;
    const int h    = rid & 15;

    short* qp = qkv + (size_t)l * QKVN + h * DHEAD;
    short* kp = qp + DMODEL;

    float q = bf2f(qp[lane]);
    float k = bf2f(kp[lane]);

    float sq = q * q, sk = k * k;
    #pragma unroll
    for (int o = 32; o > 0; o >>= 1) {
        sq += __shfl_xor(sq, o);
        sk += __shfl_xor(sk, o);
    }
    const float ss = sqrtf(fabsf(scale[h]) + 1e-8f);
    q *= ss * rsqrtf(sq + 1e-8f);
    k *= ss * rsqrtf(sk + 1e-8f);

    const int   j  = lane & 31;
    const float p  = pos[l * 2 + (j < 16 ? 1 : 0)];
    const float fj = (j < 16) ? freqs[256 + h * 16 + j] : freqs[h * 16 + (j - 16)];
    const float th = (p * 2.0f - 1.0f) * fj;
    const float cs = cosf(th), sn = sinf(th);

    const float qo = __shfl_xor(q, 32);
    const float ko = __shfl_xor(k, 32);
    const float qr = (lane < 32) ? q * cs - qo * sn : q * cs + qo * sn;
    const float kr = (lane < 32) ? k * cs - ko * sn : k * cs + ko * sn;

    qp[lane] = f2bf(qr);
    kp[lane] = f2bf(kr);
}

// ---------------------------------------------------------------------------
// Flash attention, 4 waves x 32 q = 128 q rows / block, KVBLK=64.
// K double-buffered via global_load_lds (pre-swizzled source); V reg-staged
// (issue early, ds_write late); P via per-wave swizzled LDS scratch.
// CAUSAL: pokes (normalized out).  !CAUSAL: query kv-split partials.
// ---------------------------------------------------------------------------
template<bool CAUSAL>
__global__ __launch_bounds__(256) void attn_flash(
    const short* __restrict__ qkv, short* __restrict__ outb, float* __restrict__ pml)
{
    __shared__ short Kl[2][64 * 64];
    __shared__ short VTl[2][64 * 64];
    __shared__ short Pl[4][32 * 64];

    const int h = blockIdx.y;
    const int t = threadIdx.x, lane = t & 63, w = t >> 6;
    const int c = lane & 15, g = lane >> 4;
    const int qcol = h * DHEAD, kcol = DMODEL + h * DHEAD, vcol = 2 * DMODEL + h * DHEAD;

    int q0, kt0, ktn;
    if (CAUSAL) {
        const int qt = gridDim.x - 1 - blockIdx.x;     // heavy blocks first
        q0 = qt * 128; kt0 = 0; ktn = 2 * qt + 2;
    } else {
        q0 = SPOKES + blockIdx.x * 128;
        kt0 = blockIdx.z * QTILES; ktn = QTILES;
    }

    // Q fragments: frag f covers q rows q0 + w*32 + f*16 + c
    bf16x8 qf[2][2];
    #pragma unroll
    for (int f = 0; f < 2; ++f) {
        const short* qrow = qkv + (size_t)(q0 + w * 32 + f * 16 + c) * QKVN + qcol;
        qf[f][0] = *(const bf16x8*)(qrow + g * 8);
        qf[f][1] = *(const bf16x8*)(qrow + 32 + g * 8);
    }

    float m[2] = {-INFINITY, -INFINITY}, l[2] = {0.0f, 0.0f};
    f32x4 acc[2][4] = {};
    bf16x8 vreg[2];

    // ---- staging helpers ----
    auto KDMA = [&](int buf, int kt) {
        const int k0 = kt * 64;
        #pragma unroll
        for (int i = 0; i < 2; ++i) {
            const int ch = i * 256 + t;                 // 16B chunk index
            const int kv = ch >> 3, s = ch & 7;
            const int o = s ^ ((kv & 7) ^ (kv >> 3));   // pre-swizzled source octet
            gload_lds16(qkv + (size_t)(k0 + kv) * QKVN + kcol + o * 8,
                        (char*)Kl[buf] + i * 4096 + w * 1024);
        }
    };
    auto VLOAD = [&](int kt) {
        const int k0 = kt * 64;
        const short* vrow = qkv + (size_t)(k0 + (t >> 2)) * QKVN + vcol;
        vreg[0] = *(const bf16x8*)(vrow + (t & 3) * 8);
        vreg[1] = *(const bf16x8*)(vrow + (t & 3) * 8 + 32);
    };
    auto VWRITE = [&](int buf) {
        const int kv = t >> 2;
        #pragma unroll
        for (int i = 0; i < 2; ++i) {
            const int o = (t & 3) + 4 * i;
            #pragma unroll
            for (int j = 0; j < 8; ++j) {
                const int d = o * 8 + j;
                *(short*)((char*)VTl[buf] + d * 128 + ((kv * 2) ^ swz(d))) = vreg[i][j];
            }
        }
    };

    // ---- prologue: stage tile kt0 into buffer 0 ----
    VLOAD(kt0);
    KDMA(0, kt0);
    VWRITE(0);
    __syncthreads();

    for (int it = 0; it < ktn; ++it) {
        const int kt = kt0 + it;
        const int cur = it & 1, nxt = cur ^ 1;
        const int k0 = kt * 64;

        if (it + 1 < ktn) { VLOAD(kt + 1); KDMA(nxt, kt + 1); }   // async prefetch

        const bool live0 = !CAUSAL || (k0 <= q0 + w * 32 + 15);
        const bool live1 = !CAUSAL || (k0 <= q0 + w * 32 + 31);

        // ---- S^T = K . Q^T (K frags shared across both q-frags) ----
        f32x4 st[2][4];
        #pragma unroll
        for (int mt = 0; mt < 4; ++mt) {
            const int kvr = mt * 16 + c;
            bf16x8 ka = *(const bf16x8*)((const char*)Kl[cur] + kvr * 128 + ((g * 16) ^ swz(kvr)));
            bf16x8 kb = *(const bf16x8*)((const char*)Kl[cur] + kvr * 128 + ((64 + g * 16) ^ swz(kvr)));
            if (live0) {
                f32x4 z = {0.f, 0.f, 0.f, 0.f};
                z = __builtin_amdgcn_mfma_f32_16x16x32_bf16(ka, qf[0][0], z, 0, 0, 0);
                st[0][mt] = __builtin_amdgcn_mfma_f32_16x16x32_bf16(kb, qf[0][1], z, 0, 0, 0);
            }
            if (live1) {
                f32x4 z = {0.f, 0.f, 0.f, 0.f};
                z = __builtin_amdgcn_mfma_f32_16x16x32_bf16(ka, qf[1][0], z, 0, 0, 0);
                st[1][mt] = __builtin_amdgcn_mfma_f32_16x16x32_bf16(kb, qf[1][1], z, 0, 0, 0);
            }
        }

        // ---- online softmax per frag; P -> per-wave LDS scratch ----
        #pragma unroll
        for (int f = 0; f < 2; ++f) {
            if (f == 0 ? !live0 : !live1) continue;
            const int qg = q0 + w * 32 + f * 16 + c;
            if (CAUSAL && (k0 + 63 > q0 + w * 32 + f * 16)) {
                #pragma unroll
                for (int mt = 0; mt < 4; ++mt)
                    #pragma unroll
                    for (int r = 0; r < 4; ++r)
                        if (k0 + mt * 16 + g * 4 + r > qg) st[f][mt][r] = -INFINITY;
            }
            float tmax = -INFINITY;
            #pragma unroll
            for (int mt = 0; mt < 4; ++mt)
                #pragma unroll
                for (int r = 0; r < 4; ++r) tmax = fmaxf(tmax, st[f][mt][r]);
            tmax = fmaxf(tmax, __shfl_xor(tmax, 16));
            tmax = fmaxf(tmax, __shfl_xor(tmax, 32));
            const float mnew = fmaxf(m[f], tmax);
            const float pfac = __expf(m[f] - mnew);
            float rs = 0.0f;
            const int qrow = f * 16 + c;
            #pragma unroll
            for (int mt = 0; mt < 4; ++mt) {
                bf16x4 pw;
                #pragma unroll
                for (int r = 0; r < 4; ++r) {
                    const float e = __expf(st[f][mt][r] - mnew);
                    rs += e;
                    pw[r] = f2bf(e);
                }
                *(bf16x4*)((char*)Pl[w] + qrow * 128 + ((mt * 32 + g * 8) ^ swz(qrow))) = pw;
            }
            rs += __shfl_xor(rs, 16);
            rs += __shfl_xor(rs, 32);
            l[f] = l[f] * pfac + rs;
            m[f] = mnew;
            #pragma unroll
            for (int dt = 0; dt < 4; ++dt)
                #pragma unroll
                for (int r = 0; r < 4; ++r) acc[f][dt][r] *= pfac;
        }

        // ---- PV: out^T += V^T . P^T (V frags shared across both q-frags) ----
        #pragma unroll
        for (int kc = 0; kc < 2; ++kc) {
            bf16x8 vf[4];
            #pragma unroll
            for (int dt = 0; dt < 4; ++dt) {
                const int d = dt * 16 + c;
                vf[dt] = *(const bf16x8*)((const char*)VTl[cur] + d * 128 + ((kc * 64 + g * 16) ^ swz(d)));
            }
            #pragma unroll
            for (int f = 0; f < 2; ++f) {
                if (f == 0 ? !live0 : !live1) continue;
                const int qrow = f * 16 + c;
                bf16x8 pb = *(const bf16x8*)((const char*)Pl[w] + qrow * 128 + ((kc * 64 + g * 16) ^ swz(qrow)));
                #pragma unroll
                for (int dt = 0; dt < 4; ++dt)
                    acc[f][dt] = __builtin_amdgcn_mfma_f32_16x16x32_bf16(vf[dt], pb, acc[f][dt], 0, 0, 0);
            }
        }

        if (it + 1 < ktn) VWRITE(nxt);    // reg2 arrived during compute
        __syncthreads();                  // drains KDMA; all readers done with cur
    }

    // ---- epilogue ----
    if (CAUSAL) {
        #pragma unroll
        for (int f = 0; f < 2; ++f) {
            const float inv = 1.0f / l[f];
            short* orow = outb + (size_t)(q0 + w * 32 + f * 16 + c) * DMODEL + qcol;
            #pragma unroll
            for (int dt = 0; dt < 4; ++dt)
                #pragma unroll
                for (int r = 0; r < 4; ++r)
                    orow[dt * 16 + g * 4 + r] = f2bf(acc[f][dt][r] * inv);
        }
    } else {
        if (blockIdx.z == 0) {
            // fold in the self term (only split 0)
            #pragma unroll
            for (int f = 0; f < 2; ++f) {
                const int qg = q0 + w * 32 + f * 16 + c;
                float ss = 0.0f;
                #pragma unroll
                for (int kc = 0; kc < 2; ++kc) {
                    bf16x8 ks = *(const bf16x8*)(qkv + (size_t)qg * QKVN + kcol + kc * 32 + g * 8);
                    #pragma unroll
                    for (int j = 0; j < 8; ++j) ss += bf2f(qf[f][kc][j]) * bf2f(ks[j]);
                }
                ss += __shfl_xor(ss, 16);
                ss += __shfl_xor(ss, 32);
                const float mnew = fmaxf(m[f], ss);
                const float pf = __expf(m[f] - mnew);
                const float ps = __expf(ss - mnew);
                const short* vrow = qkv + (size_t)qg * QKVN + vcol;
                #pragma unroll
                for (int dt = 0; dt < 4; ++dt) {
                    bf16x4 vs = *(const bf16x4*)(vrow + dt * 16 + g * 4);
                    #pragma unroll
                    for (int r = 0; r < 4; ++r)
                        acc[f][dt][r] = acc[f][dt][r] * pf + ps * bf2f(vs[r]);
                }
                l[f] = l[f] * pf + ps;
                m[f] = mnew;
            }
        }
        const int z = blockIdx.z;
        #pragma unroll
        for (int f = 0; f < 2; ++f) {
            const int ql = q0 - SPOKES + w * 32 + f * 16 + c;
            short* prow = outb + ((size_t)z * NQUERY + ql) * DMODEL + qcol;
            #pragma unroll
            for (int dt = 0; dt < 4; ++dt)
                #pragma unroll
                for (int r = 0; r < 4; ++r)
                    prow[dt * 16 + g * 4 + r] = f2bf(acc[f][dt][r]);
            if (g == 0) {
                float* mlp = pml + (((size_t)z * NH + h) * NQUERY + ql) * 2;
                mlp[0] = m[f];
                mlp[1] = l[f];
            }
        }
    }
}

// ---------------------------------------------------------------------------
// Combine kv-split partials: out = sum_z e^{m_z-M} acc_z / sum_z e^{m_z-M} l_z
// ---------------------------------------------------------------------------
__global__ __launch_bounds__(256) void attn_combine(
    const short* __restrict__ pacc, const float* __restrict__ pml,
    short* __restrict__ attnb)
{
    const int i = blockIdx.x * 256 + threadIdx.x;     // [0, NQUERY*NH*8)
    const int ql = i >> 7;
    const int h  = (i >> 3) & 15;
    const int o  = i & 7;

    float mz[NSPLIT], lz[NSPLIT];
    float M = -INFINITY;
    #pragma unroll
    for (int z = 0; z < NSPLIT; ++z) {
        const float* p = pml + (((size_t)z * NH + h) * NQUERY + ql) * 2;
        mz[z] = p[0]; lz[z] = p[1];
        M = fmaxf(M, mz[z]);
    }
    float L = 0.0f, wz[NSPLIT];
    #pragma unroll
    for (int z = 0; z < NSPLIT; ++z) { wz[z] = __expf(mz[z] - M); L += wz[z] * lz[z]; }

    float outv[8] = {};
    #pragma unroll
    for (int z = 0; z < NSPLIT; ++z) {
        bf16x8 a = *(const bf16x8*)(pacc + ((size_t)z * NQUERY + ql) * DMODEL + h * 64 + o * 8);
        #pragma unroll
        for (int j = 0; j < 8; ++j) outv[j] += wz[z] * bf2f(a[j]);
    }
    const float inv = 1.0f / L;
    bf16x8 r;
    #pragma unroll
    for (int j = 0; j < 8; ++j) r[j] = f2bf(outv[j] * inv);
    *(bf16x8*)(attnb + (size_t)(SPOKES + ql) * DMODEL + h * 64 + o * 8) = r;
}

// ---------------------------------------------------------------------------
extern "C" void kernel_launch(void* const* d_in, const int* in_sizes, int n_in,
                              void* d_out, int out_size, void* d_ws, size_t ws_size,
                              hipStream_t stream)
{
    const float* x      = (const float*)d_in[0];
    const float* pos    = (const float*)d_in[1];
    const float* qkv_w  = (const float*)d_in[2];
    const float* out_w  = (const float*)d_in[3];
    const float* scale  = (const float*)d_in[4];
    const float* freqs  = (const float*)d_in[5];
    float*       out    = (float*)d_out;

    char* ws = (char*)d_ws;
    short* qkv_bf  = (short*)(ws);                                   // 24 MB
    short* x_bf    = (short*)(ws + (size_t)24 * 1024 * 1024);        //  8 MB (pacc after gemm1)
    short* wqkv_bf = (short*)(ws + (size_t)32 * 1024 * 1024);        //  6 MB (pml after gemm1)
    short* wout_bf = (short*)(ws + (size_t)38 * 1024 * 1024);        //  2 MB
    short* attn_bf = (short*)(ws + (size_t)40 * 1024 * 1024);        //  8 MB
    short* pacc    = x_bf;                                           // reuse (dead after gemm1)
    float* pml     = (float*)wqkv_bf;                                // reuse (dead after gemm1)

    const dim3 blk(256);

    cvt_f32_bf16<<<dim3(SEQL * DMODEL / 8 / 256), blk, 0, stream>>>(x, x_bf, SEQL * DMODEL / 8);
    cvt_f32_bf16<<<dim3(QKVN * DMODEL / 8 / 256), blk, 0, stream>>>(qkv_w, wqkv_bf, QKVN * DMODEL / 8);
    cvt_f32_bf16<<<dim3(DMODEL * DMODEL / 8 / 256), blk, 0, stream>>>(out_w, wout_bf, DMODEL * DMODEL / 8);

    // 1) qkv = x @ qkv_w^T  (bf16 in, bf16 out)
    gemm_bf16<true><<<dim3(QKVN / 128, SEQL / 128), blk, 0, stream>>>(
        x_bf, wqkv_bf, qkv_bf, DMODEL, QKVN);

    // 2) cos-scale + axial rope on q,k (in place, bf16)
    transform_qk<<<dim3(SEQL * NH / 4), blk, 0, stream>>>(qkv_bf, pos, scale, freqs);

    // 3) causal attention over pokes -> attn_bf rows [0, SPOKES)
    attn_flash<true><<<dim3(SPOKES / 128, NH), blk, 0, stream>>>(qkv_bf, attn_bf, nullptr);

    // 4) query attention, kv-split x4 -> partials, then combine
    attn_flash<false><<<dim3(NQUERY / 128, NH, NSPLIT), blk, 0, stream>>>(qkv_bf, pacc, pml);
    attn_combine<<<dim3(NQUERY * NH * 8 / 256), blk, 0, stream>>>(pacc, pml, attn_bf);

    // 5) out = attn @ out_w^T  (bf16 in, f32 out)
    gemm_bf16<false><<<dim3(DMODEL / 128, SEQL / 128), blk, 0, stream>>>(
        attn_bf, wout_bf, out, DMODEL, DMODEL);
}

// Round 5
// 246.145 us; speedup vs baseline: 8.7991x; 1.0682x over previous
//
#include <hip/hip_runtime.h>
#include <math.h>

#define SEQL   4096
#define DMODEL 1024
#define NH     16
#define DHEAD  64
#define SPOKES 3072
#define NQUERY (SEQL - SPOKES)     // 1024
#define QKVN   (3 * DMODEL)        // 3072

// causal schedule: 24 q-tiles of 128 rows; qt>=12 split into 2 kv-chunks
#define NQT      24
#define NHEAVY   12                // q-tiles 12..23 are split
#define CGRID    (NHEAVY + 2 * (NQT - NHEAVY))   // 12 light + 24 heavy chunks = 36
#define HROWS    1536              // rows 1536..3071 have partials
#define HBASE    1536
// query schedule
#define NSPLIT_Q 3
#define QTILES   (SPOKES / 64 / NSPLIT_Q)        // 16 tiles per split

typedef short bf16x8 __attribute__((ext_vector_type(8)));
typedef short bf16x4 __attribute__((ext_vector_type(4)));
typedef float f32x4  __attribute__((ext_vector_type(4)));

__device__ __forceinline__ short f2bf(float f) {
    unsigned u = __builtin_bit_cast(unsigned, f);
    u += 0x7fffu + ((u >> 16) & 1u);     // RNE
    return (short)(u >> 16);
}
__device__ __forceinline__ float bf2f(short s) {
    unsigned u = ((unsigned)(unsigned short)s) << 16;
    return __builtin_bit_cast(float, u);
}
// XOR swizzle on byte bits 4..6, keyed by LDS row (rows are 128B).
__device__ __forceinline__ int swz(int row) { return ((row & 7) ^ (row >> 3)) << 4; }

// async global->LDS, 16B per lane; LDS dest = wave-uniform base + lane*16
__device__ __forceinline__ void gload_lds16(const void* g, void* l) {
    __builtin_amdgcn_global_load_lds(
        (const __attribute__((address_space(1))) unsigned int*)g,
        (__attribute__((address_space(3))) unsigned int*)l,
        16, 0, 0);
}

// ---------------------------------------------------------------------------
// f32 -> bf16 conversion, 8 elems/thread
// ---------------------------------------------------------------------------
__global__ __launch_bounds__(256) void cvt_f32_bf16(
    const float* __restrict__ in, short* __restrict__ out, int n8)
{
    const int i = blockIdx.x * 256 + threadIdx.x;
    if (i >= n8) return;
    float4 a = ((const float4*)in)[i * 2];
    float4 b = ((const float4*)in)[i * 2 + 1];
    bf16x8 v;
    v[0] = f2bf(a.x); v[1] = f2bf(a.y); v[2] = f2bf(a.z); v[3] = f2bf(a.w);
    v[4] = f2bf(b.x); v[5] = f2bf(b.y); v[6] = f2bf(b.z); v[7] = f2bf(b.w);
    ((bf16x8*)out)[i] = v;
}

// ---------------------------------------------------------------------------
// bf16 MFMA GEMM (unchanged): C = A * B^T, 128x128 tile, BK=64.
// ---------------------------------------------------------------------------
template<bool BF16OUT>
__global__ __launch_bounds__(256) void gemm_bf16(
    const short* __restrict__ A, const short* __restrict__ B, void* __restrict__ Cv,
    int K, int ldc)
{
    __shared__ short As[128 * 64];
    __shared__ short Bs[128 * 64];

    const int t = threadIdx.x;
    const int lane = t & 63, w = t >> 6;
    const int c = lane & 15, g = lane >> 4;
    const int wr = w >> 1, wc = w & 1;
    const int m0 = blockIdx.y * 128, n0 = blockIdx.x * 128;

    f32x4 acc[4][4] = {};

    for (int k0 = 0; k0 < K; k0 += 64) {
        __syncthreads();
        #pragma unroll
        for (int i = 0; i < 4; ++i) {
            const int chunk = (w * 4 + i) * 64 + lane;
            const int row = chunk >> 3, cc = chunk & 7;
            gload_lds16(A + (size_t)(m0 + row) * K + k0 + cc * 8,
                        As + (size_t)(w * 4 + i) * 512);
            gload_lds16(B + (size_t)(n0 + row) * K + k0 + cc * 8,
                        Bs + (size_t)(w * 4 + i) * 512);
        }
        __syncthreads();

        #pragma unroll
        for (int kk = 0; kk < 2; ++kk) {
            bf16x8 af[4], bf[4];
            #pragma unroll
            for (int i = 0; i < 4; ++i)
                af[i] = *(const bf16x8*)(As + (wr * 64 + i * 16 + c) * 64 + kk * 32 + g * 8);
            #pragma unroll
            for (int j = 0; j < 4; ++j)
                bf[j] = *(const bf16x8*)(Bs + (wc * 64 + j * 16 + c) * 64 + kk * 32 + g * 8);
            #pragma unroll
            for (int i = 0; i < 4; ++i)
                #pragma unroll
                for (int j = 0; j < 4; ++j)
                    acc[i][j] = __builtin_amdgcn_mfma_f32_16x16x32_bf16(af[i], bf[j], acc[i][j], 0, 0, 0);
        }
    }

    #pragma unroll
    for (int i = 0; i < 4; ++i)
        #pragma unroll
        for (int r = 0; r < 4; ++r) {
            const int row = m0 + wr * 64 + i * 16 + g * 4 + r;
            #pragma unroll
            for (int j = 0; j < 4; ++j) {
                const int col = n0 + wc * 64 + j * 16 + c;
                const float v = acc[i][j][r];
                if (BF16OUT) ((short*)Cv)[(size_t)row * ldc + col] = f2bf(v);
                else         ((float*)Cv)[(size_t)row * ldc + col] = v;
            }
        }
}

// ---------------------------------------------------------------------------
// In-place cos-scale + axial RoPE on bf16 q and k (unchanged).
// ---------------------------------------------------------------------------
__global__ __launch_bounds__(256) void transform_qk(
    short* __restrict__ qkv, const float* __restrict__ pos,
    const float* __restrict__ scale, const float* __restrict__ freqs)
{
    const int w    = threadIdx.x >> 6;
    const int lane = threadIdx.x & 63;
    const int rid  = blockIdx.x * 4 + w;
    const int l    = rid >> 4;
    const int h    = rid & 15;

    short* qp = qkv + (size_t)l * QKVN + h * DHEAD;
    short* kp = qp + DMODEL;

    float q = bf2f(qp[lane]);
    float k = bf2f(kp[lane]);

    float sq = q * q, sk = k * k;
    #pragma unroll
    for (int o = 32; o > 0; o >>= 1) {
        sq += __shfl_xor(sq, o);
        sk += __shfl_xor(sk, o);
    }
    const float ss = sqrtf(fabsf(scale[h]) + 1e-8f);
    q *= ss * rsqrtf(sq + 1e-8f);
    k *= ss * rsqrtf(sk + 1e-8f);

    const int   j  = lane & 31;
    const float p  = pos[l * 2 + (j < 16 ? 1 : 0)];
    const float fj = (j < 16) ? freqs[256 + h * 16 + j] : freqs[h * 16 + (j - 16)];
    const float th = (p * 2.0f - 1.0f) * fj;
    const float cs = cosf(th), sn = sinf(th);

    const float qo = __shfl_xor(q, 32);
    const float ko = __shfl_xor(k, 32);
    const float qr = (lane < 32) ? q * cs - qo * sn : q * cs + qo * sn;
    const float kr = (lane < 32) ? k * cs - ko * sn : k * cs + ko * sn;

    qp[lane] = f2bf(qr);
    kp[lane] = f2bf(kr);
}

// ---------------------------------------------------------------------------
// Flash attention, 4 waves x 32 q = 128 q rows / block, KVBLK=64.
// K double-buffered via global_load_lds (pre-swizzled source); V reg-staged
// (issue early, ds_write late); P via per-wave swizzled LDS scratch.
// CAUSAL: pokes. Light q-tiles (qt<12) write normalized output directly;
// heavy q-tiles are kv-split x2 and write unnormalized partials + (m,l).
// !CAUSAL: query rows, kv-split x3 partials (split 0 folds the self term).
// ---------------------------------------------------------------------------
template<bool CAUSAL>
__global__ __launch_bounds__(256) void attn_flash(
    const short* __restrict__ qkv, short* __restrict__ outb,
    short* __restrict__ pacc, float* __restrict__ pml)
{
    __shared__ short Kl[2][64 * 64];
    __shared__ short VTl[2][64 * 64];
    __shared__ short Pl[4][32 * 64];

    const int h = blockIdx.y;
    const int t = threadIdx.x, lane = t & 63, w = t >> 6;
    const int c = lane & 15, g = lane >> 4;
    const int qcol = h * DHEAD, kcol = DMODEL + h * DHEAD, vcol = 2 * DMODEL + h * DHEAD;

    int q0, kt0, ktn, z;
    bool partial;
    if (CAUSAL) {
        const int x = blockIdx.x;
        if (x < 2 * (NQT - NHEAVY)) {            // heavy chunks first
            const int qt = NQT - 1 - (x >> 1);   // 23..12
            z = x & 1;
            const int half = qt + 1;             // ktn = 2qt+2, halves of qt+1 tiles
            q0 = qt * 128; kt0 = z * half; ktn = half; partial = true;
        } else {
            const int qt = CGRID - 1 - x;        // 11..0
            z = 0;
            q0 = qt * 128; kt0 = 0; ktn = 2 * qt + 2; partial = false;
        }
    } else {
        q0 = SPOKES + blockIdx.x * 128;
        z = blockIdx.z;
        kt0 = z * QTILES; ktn = QTILES; partial = true;
    }

    // Q fragments: frag f covers q rows q0 + w*32 + f*16 + c
    bf16x8 qf[2][2];
    #pragma unroll
    for (int f = 0; f < 2; ++f) {
        const short* qrow = qkv + (size_t)(q0 + w * 32 + f * 16 + c) * QKVN + qcol;
        qf[f][0] = *(const bf16x8*)(qrow + g * 8);
        qf[f][1] = *(const bf16x8*)(qrow + 32 + g * 8);
    }

    float m[2] = {-INFINITY, -INFINITY}, l[2] = {0.0f, 0.0f};
    f32x4 acc[2][4] = {};
    bf16x8 vreg[2];

    // ---- staging helpers ----
    auto KDMA = [&](int buf, int kt) {
        const int k0 = kt * 64;
        #pragma unroll
        for (int i = 0; i < 2; ++i) {
            const int ch = i * 256 + t;                 // 16B chunk index
            const int kv = ch >> 3, s = ch & 7;
            const int o = s ^ ((kv & 7) ^ (kv >> 3));   // pre-swizzled source octet
            gload_lds16(qkv + (size_t)(k0 + kv) * QKVN + kcol + o * 8,
                        (char*)Kl[buf] + i * 4096 + w * 1024);
        }
    };
    auto VLOAD = [&](int kt) {
        const int k0 = kt * 64;
        const short* vrow = qkv + (size_t)(k0 + (t >> 2)) * QKVN + vcol;
        vreg[0] = *(const bf16x8*)(vrow + (t & 3) * 8);
        vreg[1] = *(const bf16x8*)(vrow + (t & 3) * 8 + 32);
    };
    auto VWRITE = [&](int buf) {
        const int kv = t >> 2;
        #pragma unroll
        for (int i = 0; i < 2; ++i) {
            const int o = (t & 3) + 4 * i;
            #pragma unroll
            for (int j = 0; j < 8; ++j) {
                const int d = o * 8 + j;
                *(short*)((char*)VTl[buf] + d * 128 + ((kv * 2) ^ swz(d))) = vreg[i][j];
            }
        }
    };

    // ---- prologue: stage tile kt0 into buffer 0 ----
    VLOAD(kt0);
    KDMA(0, kt0);
    VWRITE(0);
    __syncthreads();

    for (int it = 0; it < ktn; ++it) {
        const int kt = kt0 + it;
        const int cur = it & 1, nxt = cur ^ 1;
        const int k0 = kt * 64;

        if (it + 1 < ktn) { VLOAD(kt + 1); KDMA(nxt, kt + 1); }   // async prefetch

        const bool live0 = !CAUSAL || (k0 <= q0 + w * 32 + 15);
        const bool live1 = !CAUSAL || (k0 <= q0 + w * 32 + 31);

        // ---- S^T = K . Q^T ----
        f32x4 st[2][4];
        #pragma unroll
        for (int mt = 0; mt < 4; ++mt) {
            const int kvr = mt * 16 + c;
            bf16x8 ka = *(const bf16x8*)((const char*)Kl[cur] + kvr * 128 + ((g * 16) ^ swz(kvr)));
            bf16x8 kb = *(const bf16x8*)((const char*)Kl[cur] + kvr * 128 + ((64 + g * 16) ^ swz(kvr)));
            if (live0) {
                f32x4 zz = {0.f, 0.f, 0.f, 0.f};
                zz = __builtin_amdgcn_mfma_f32_16x16x32_bf16(ka, qf[0][0], zz, 0, 0, 0);
                st[0][mt] = __builtin_amdgcn_mfma_f32_16x16x32_bf16(kb, qf[0][1], zz, 0, 0, 0);
            }
            if (live1) {
                f32x4 zz = {0.f, 0.f, 0.f, 0.f};
                zz = __builtin_amdgcn_mfma_f32_16x16x32_bf16(ka, qf[1][0], zz, 0, 0, 0);
                st[1][mt] = __builtin_amdgcn_mfma_f32_16x16x32_bf16(kb, qf[1][1], zz, 0, 0, 0);
            }
        }

        // ---- online softmax per frag; P -> per-wave LDS scratch ----
        #pragma unroll
        for (int f = 0; f < 2; ++f) {
            if (f == 0 ? !live0 : !live1) continue;
            const int qg = q0 + w * 32 + f * 16 + c;
            if (CAUSAL && (k0 + 63 > q0 + w * 32 + f * 16)) {
                #pragma unroll
                for (int mt = 0; mt < 4; ++mt)
                    #pragma unroll
                    for (int r = 0; r < 4; ++r)
                        if (k0 + mt * 16 + g * 4 + r > qg) st[f][mt][r] = -INFINITY;
            }
            float tmax = -INFINITY;
            #pragma unroll
            for (int mt = 0; mt < 4; ++mt)
                #pragma unroll
                for (int r = 0; r < 4; ++r) tmax = fmaxf(tmax, st[f][mt][r]);
            tmax = fmaxf(tmax, __shfl_xor(tmax, 16));
            tmax = fmaxf(tmax, __shfl_xor(tmax, 32));
            const float mnew = fmaxf(m[f], tmax);
            const float pfac = __expf(m[f] - mnew);
            float rs = 0.0f;
            const int qrow = f * 16 + c;
            #pragma unroll
            for (int mt = 0; mt < 4; ++mt) {
                bf16x4 pw;
                #pragma unroll
                for (int r = 0; r < 4; ++r) {
                    const float e = __expf(st[f][mt][r] - mnew);
                    rs += e;
                    pw[r] = f2bf(e);
                }
                *(bf16x4*)((char*)Pl[w] + qrow * 128 + ((mt * 32 + g * 8) ^ swz(qrow))) = pw;
            }
            rs += __shfl_xor(rs, 16);
            rs += __shfl_xor(rs, 32);
            l[f] = l[f] * pfac + rs;
            m[f] = mnew;
            #pragma unroll
            for (int dt = 0; dt < 4; ++dt)
                #pragma unroll
                for (int r = 0; r < 4; ++r) acc[f][dt][r] *= pfac;
        }

        // ---- PV: out^T += V^T . P^T ----
        #pragma unroll
        for (int kc = 0; kc < 2; ++kc) {
            bf16x8 vf[4];
            #pragma unroll
            for (int dt = 0; dt < 4; ++dt) {
                const int d = dt * 16 + c;
                vf[dt] = *(const bf16x8*)((const char*)VTl[cur] + d * 128 + ((kc * 64 + g * 16) ^ swz(d)));
            }
            #pragma unroll
            for (int f = 0; f < 2; ++f) {
                if (f == 0 ? !live0 : !live1) continue;
                const int qrow = f * 16 + c;
                bf16x8 pb = *(const bf16x8*)((const char*)Pl[w] + qrow * 128 + ((kc * 64 + g * 16) ^ swz(qrow)));
                #pragma unroll
                for (int dt = 0; dt < 4; ++dt)
                    acc[f][dt] = __builtin_amdgcn_mfma_f32_16x16x32_bf16(vf[dt], pb, acc[f][dt], 0, 0, 0);
            }
        }

        if (it + 1 < ktn) VWRITE(nxt);    // reg data arrived during compute
        __syncthreads();                  // drains KDMA; all readers done with cur
    }

    // ---- epilogue ----
    if (!CAUSAL && z == 0) {
        // fold in the self term (split 0 only)
        #pragma unroll
        for (int f = 0; f < 2; ++f) {
            const int qg = q0 + w * 32 + f * 16 + c;
            float ss = 0.0f;
            #pragma unroll
            for (int kc = 0; kc < 2; ++kc) {
                bf16x8 ks = *(const bf16x8*)(qkv + (size_t)qg * QKVN + kcol + kc * 32 + g * 8);
                #pragma unroll
                for (int j = 0; j < 8; ++j) ss += bf2f(qf[f][kc][j]) * bf2f(ks[j]);
            }
            ss += __shfl_xor(ss, 16);
            ss += __shfl_xor(ss, 32);
            const float mnew = fmaxf(m[f], ss);
            const float pf = __expf(m[f] - mnew);
            const float ps = __expf(ss - mnew);
            const short* vrow = qkv + (size_t)qg * QKVN + vcol;
            #pragma unroll
            for (int dt = 0; dt < 4; ++dt) {
                bf16x4 vs = *(const bf16x4*)(vrow + dt * 16 + g * 4);
                #pragma unroll
                for (int r = 0; r < 4; ++r)
                    acc[f][dt][r] = acc[f][dt][r] * pf + ps * bf2f(vs[r]);
            }
            l[f] = l[f] * pf + ps;
            m[f] = mnew;
        }
    }

    if (CAUSAL && !partial) {
        #pragma unroll
        for (int f = 0; f < 2; ++f) {
            const float inv = 1.0f / l[f];
            short* orow = outb + (size_t)(q0 + w * 32 + f * 16 + c) * DMODEL + qcol;
            #pragma unroll
            for (int dt = 0; dt < 4; ++dt)
                #pragma unroll
                for (int r = 0; r < 4; ++r)
                    orow[dt * 16 + g * 4 + r] = f2bf(acc[f][dt][r] * inv);
        }
    } else {
        const int rowbase = CAUSAL ? HBASE : SPOKES;
        const int nrows   = CAUSAL ? HROWS : NQUERY;
        #pragma unroll
        for (int f = 0; f < 2; ++f) {
            const int pr = q0 - rowbase + w * 32 + f * 16 + c;
            short* prow = pacc + ((size_t)z * nrows + pr) * DMODEL + qcol;
            #pragma unroll
            for (int dt = 0; dt < 4; ++dt)
                #pragma unroll
                for (int r = 0; r < 4; ++r)
                    prow[dt * 16 + g * 4 + r] = f2bf(acc[f][dt][r]);
            if (g == 0) {
                float* mlp = pml + (((size_t)z * NH + h) * nrows + pr) * 2;
                mlp[0] = m[f];
                mlp[1] = l[f];
            }
        }
    }
}

// ---------------------------------------------------------------------------
// Combine kv-split partials: out = sum_z e^{m_z-M} acc_z / sum_z e^{m_z-M} l_z
// ---------------------------------------------------------------------------
template<int NS>
__global__ __launch_bounds__(256) void attn_combine(
    const short* __restrict__ pacc, const float* __restrict__ pml,
    short* __restrict__ attnb, int nrows, int rowbase)
{
    const int i = blockIdx.x * 256 + threadIdx.x;     // [0, nrows*NH*8)
    const int r = i >> 7;
    const int h = (i >> 3) & 15;
    const int o = i & 7;

    float mz[NS], lz[NS];
    float M = -INFINITY;
    #pragma unroll
    for (int z = 0; z < NS; ++z) {
        const float* p = pml + (((size_t)z * NH + h) * nrows + r) * 2;
        mz[z] = p[0]; lz[z] = p[1];
        M = fmaxf(M, mz[z]);
    }
    float L = 0.0f, wz[NS];
    #pragma unroll
    for (int z = 0; z < NS; ++z) { wz[z] = __expf(mz[z] - M); L += wz[z] * lz[z]; }

    float outv[8] = {};
    #pragma unroll
    for (int z = 0; z < NS; ++z) {
        bf16x8 a = *(const bf16x8*)(pacc + ((size_t)z * nrows + r) * DMODEL + h * 64 + o * 8);
        #pragma unroll
        for (int j = 0; j < 8; ++j) outv[j] += wz[z] * bf2f(a[j]);
    }
    const float inv = 1.0f / L;
    bf16x8 res;
    #pragma unroll
    for (int j = 0; j < 8; ++j) res[j] = f2bf(outv[j] * inv);
    *(bf16x8*)(attnb + (size_t)(rowbase + r) * DMODEL + h * 64 + o * 8) = res;
}

// ---------------------------------------------------------------------------
extern "C" void kernel_launch(void* const* d_in, const int* in_sizes, int n_in,
                              void* d_out, int out_size, void* d_ws, size_t ws_size,
                              hipStream_t stream)
{
    const float* x      = (const float*)d_in[0];
    const float* pos    = (const float*)d_in[1];
    const float* qkv_w  = (const float*)d_in[2];
    const float* out_w  = (const float*)d_in[3];
    const float* scale  = (const float*)d_in[4];
    const float* freqs  = (const float*)d_in[5];
    float*       out    = (float*)d_out;

    const size_t MB = 1024 * 1024;
    char* ws = (char*)d_ws;
    short* qkv_bf  = (short*)(ws);                       // 0..24MB   qkv (live throughout)
    short* x_bf    = (short*)(ws + 24 * MB);             // 24..32MB  x, then attn
    short* wqkv_bf = (short*)(ws + 32 * MB);             // 32..38MB  qkv_w, then query pacc
    short* wout_bf = (short*)(ws + 38 * MB);             // 38..40MB  out_w
    short* pacc_c  = (short*)(ws + 40 * MB);             // 40..46MB  causal partials (2 x 1536 rows)
    float* pml_c   = (float*)(ws + 46 * MB);             // 46..46.38MB
    float* pml_q   = (float*)(ws + 46 * MB + 393216);    // 46.38..46.75MB
    short* attn_bf = x_bf;                               // alias (x dead after gemm1)
    short* pacc_q  = wqkv_bf;                            // alias (w dead after gemm1)

    const dim3 blk(256);

    cvt_f32_bf16<<<dim3(SEQL * DMODEL / 8 / 256), blk, 0, stream>>>(x, x_bf, SEQL * DMODEL / 8);
    cvt_f32_bf16<<<dim3(QKVN * DMODEL / 8 / 256), blk, 0, stream>>>(qkv_w, wqkv_bf, QKVN * DMODEL / 8);
    cvt_f32_bf16<<<dim3(DMODEL * DMODEL / 8 / 256), blk, 0, stream>>>(out_w, wout_bf, DMODEL * DMODEL / 8);

    // 1) qkv = x @ qkv_w^T  (bf16 in, bf16 out)
    gemm_bf16<true><<<dim3(QKVN / 128, SEQL / 128), blk, 0, stream>>>(
        x_bf, wqkv_bf, qkv_bf, DMODEL, QKVN);

    // 2) cos-scale + axial rope on q,k (in place, bf16)
    transform_qk<<<dim3(SEQL * NH / 4), blk, 0, stream>>>(qkv_bf, pos, scale, freqs);

    // 3) causal attention over pokes: light q-tiles direct, heavy q-tiles split x2
    attn_flash<true><<<dim3(CGRID, NH), blk, 0, stream>>>(qkv_bf, attn_bf, pacc_c, pml_c);

    // 4) query attention, kv-split x3 -> partials
    attn_flash<false><<<dim3(NQUERY / 128, NH, NSPLIT_Q), blk, 0, stream>>>(qkv_bf, nullptr, pacc_q, pml_q);

    // 5) combines -> attn_bf
    attn_combine<2><<<dim3(HROWS * NH * 8 / 256), blk, 0, stream>>>(pacc_c, pml_c, attn_bf, HROWS, HBASE);
    attn_combine<NSPLIT_Q><<<dim3(NQUERY * NH * 8 / 256), blk, 0, stream>>>(pacc_q, pml_q, attn_bf, NQUERY, SPOKES);

    // 6) out = attn @ out_w^T  (bf16 in, f32 out)
    gemm_bf16<false><<<dim3(DMODEL / 128, SEQL / 128), blk, 0, stream>>>(
        attn_bf, wout_bf, out, DMODEL, DMODEL);
}

// Round 6
// 233.699 us; speedup vs baseline: 9.2677x; 1.0533x over previous
//
#include <hip/hip_runtime.h>
#include <math.h>

#define SEQL   4096
#define DMODEL 1024
#define NH     16
#define DHEAD  64
#define SPOKES 3072
#define NQUERY (SEQL - SPOKES)     // 1024
#define QKVN   (3 * DMODEL)        // 3072

typedef short bf16x8 __attribute__((ext_vector_type(8)));
typedef short bf16x4 __attribute__((ext_vector_type(4)));
typedef float f32x4  __attribute__((ext_vector_type(4)));

__device__ __forceinline__ short f2bf(float f) {
    unsigned u = __builtin_bit_cast(unsigned, f);
    u += 0x7fffu + ((u >> 16) & 1u);     // RNE
    return (short)(u >> 16);
}
__device__ __forceinline__ float bf2f(short s) {
    unsigned u = ((unsigned)(unsigned short)s) << 16;
    return __builtin_bit_cast(float, u);
}
// XOR swizzle on byte bits 4..6, keyed by LDS row (rows are 128B).
__device__ __forceinline__ int swz(int row) { return ((row & 7) ^ (row >> 3)) << 4; }

// async global->LDS, 16B per lane; LDS dest = wave-uniform base + lane*16
__device__ __forceinline__ void gload_lds16(const void* g, void* l) {
    __builtin_amdgcn_global_load_lds(
        (const __attribute__((address_space(1))) unsigned int*)g,
        (__attribute__((address_space(3))) unsigned int*)l,
        16, 0, 0);
}

// ---------------------------------------------------------------------------
// f32 -> bf16 conversion, 8 elems/thread
// ---------------------------------------------------------------------------
__global__ __launch_bounds__(256) void cvt_f32_bf16(
    const float* __restrict__ in, short* __restrict__ out, int n8)
{
    const int i = blockIdx.x * 256 + threadIdx.x;
    if (i >= n8) return;
    float4 a = ((const float4*)in)[i * 2];
    float4 b = ((const float4*)in)[i * 2 + 1];
    bf16x8 v;
    v[0] = f2bf(a.x); v[1] = f2bf(a.y); v[2] = f2bf(a.z); v[3] = f2bf(a.w);
    v[4] = f2bf(b.x); v[5] = f2bf(b.y); v[6] = f2bf(b.z); v[7] = f2bf(b.w);
    ((bf16x8*)out)[i] = v;
}

// ---------------------------------------------------------------------------
// bf16 MFMA GEMM (unchanged): C = A * B^T, 128x128 tile, BK=64.
// ---------------------------------------------------------------------------
template<bool BF16OUT>
__global__ __launch_bounds__(256) void gemm_bf16(
    const short* __restrict__ A, const short* __restrict__ B, void* __restrict__ Cv,
    int K, int ldc)
{
    __shared__ short As[128 * 64];
    __shared__ short Bs[128 * 64];

    const int t = threadIdx.x;
    const int lane = t & 63, w = t >> 6;
    const int c = lane & 15, g = lane >> 4;
    const int wr = w >> 1, wc = w & 1;
    const int m0 = blockIdx.y * 128, n0 = blockIdx.x * 128;

    f32x4 acc[4][4] = {};

    for (int k0 = 0; k0 < K; k0 += 64) {
        __syncthreads();
        #pragma unroll
        for (int i = 0; i < 4; ++i) {
            const int chunk = (w * 4 + i) * 64 + lane;
            const int row = chunk >> 3, cc = chunk & 7;
            gload_lds16(A + (size_t)(m0 + row) * K + k0 + cc * 8,
                        As + (size_t)(w * 4 + i) * 512);
            gload_lds16(B + (size_t)(n0 + row) * K + k0 + cc * 8,
                        Bs + (size_t)(w * 4 + i) * 512);
        }
        __syncthreads();

        #pragma unroll
        for (int kk = 0; kk < 2; ++kk) {
            bf16x8 af[4], bf[4];
            #pragma unroll
            for (int i = 0; i < 4; ++i)
                af[i] = *(const bf16x8*)(As + (wr * 64 + i * 16 + c) * 64 + kk * 32 + g * 8);
            #pragma unroll
            for (int j = 0; j < 4; ++j)
                bf[j] = *(const bf16x8*)(Bs + (wc * 64 + j * 16 + c) * 64 + kk * 32 + g * 8);
            #pragma unroll
            for (int i = 0; i < 4; ++i)
                #pragma unroll
                for (int j = 0; j < 4; ++j)
                    acc[i][j] = __builtin_amdgcn_mfma_f32_16x16x32_bf16(af[i], bf[j], acc[i][j], 0, 0, 0);
        }
    }

    #pragma unroll
    for (int i = 0; i < 4; ++i)
        #pragma unroll
        for (int r = 0; r < 4; ++r) {
            const int row = m0 + wr * 64 + i * 16 + g * 4 + r;
            #pragma unroll
            for (int j = 0; j < 4; ++j) {
                const int col = n0 + wc * 64 + j * 16 + c;
                const float v = acc[i][j][r];
                if (BF16OUT) ((short*)Cv)[(size_t)row * ldc + col] = f2bf(v);
                else         ((float*)Cv)[(size_t)row * ldc + col] = v;
            }
        }
}

// ---------------------------------------------------------------------------
// In-place cos-scale + axial RoPE on bf16 q and k (unchanged).
// ---------------------------------------------------------------------------
__global__ __launch_bounds__(256) void transform_qk(
    short* __restrict__ qkv, const float* __restrict__ pos,
    const float* __restrict__ scale, const float* __restrict__ freqs)
{
    const int w    = threadIdx.x >> 6;
    const int lane = threadIdx.x & 63;
    const int rid  = blockIdx.x * 4 + w;
    const int l    = rid >> 4;
    const int h    = rid & 15;

    short* qp = qkv + (size_t)l * QKVN + h * DHEAD;
    short* kp = qp + DMODEL;

    float q = bf2f(qp[lane]);
    float k = bf2f(kp[lane]);

    float sq = q * q, sk = k * k;
    #pragma unroll
    for (int o = 32; o > 0; o >>= 1) {
        sq += __shfl_xor(sq, o);
        sk += __shfl_xor(sk, o);
    }
    const float ss = sqrtf(fabsf(scale[h]) + 1e-8f);
    q *= ss * rsqrtf(sq + 1e-8f);
    k *= ss * rsqrtf(sk + 1e-8f);

    const int   j  = lane & 31;
    const float p  = pos[l * 2 + (j < 16 ? 1 : 0)];
    const float fj = (j < 16) ? freqs[256 + h * 16 + j] : freqs[h * 16 + (j - 16)];
    const float th = (p * 2.0f - 1.0f) * fj;
    const float cs = cosf(th), sn = sinf(th);

    const float qo = __shfl_xor(q, 32);
    const float ko = __shfl_xor(k, 32);
    const float qr = (lane < 32) ? q * cs - qo * sn : q * cs + qo * sn;
    const float kr = (lane < 32) ? k * cs - ko * sn : k * cs + ko * sn;

    qp[lane] = f2bf(qr);
    kp[lane] = f2bf(kr);
}

// ---------------------------------------------------------------------------
// Fused flash attention, uniform-work chunks (<=16 kv-tiles per block).
// grid = (72, 16): x 0..23 query chunks (8 qb x 3 splits), 24..47 causal
// qt16..23 x3, 48..63 causal qt8..15 x2, 64..71 causal qt7..0 direct.
// Split-0 partials go unnormalized into attn (+pml0); extra splits into
// slot arrays pacc/pml. 4 waves x 32 q rows, KVBLK=64, K via global_load_lds
// (pre-swizzled source, double-buffered), V reg-staged, P via LDS scratch.
// ---------------------------------------------------------------------------
__global__ __launch_bounds__(256) void attn_fused(
    const short* __restrict__ qkv, short* __restrict__ attn,
    short* __restrict__ pacc_c, float* __restrict__ pml_c, float* __restrict__ pml0_c,
    short* __restrict__ pacc_q, float* __restrict__ pml_q, float* __restrict__ pml0_q)
{
    __shared__ short Kl[2][64 * 64];
    __shared__ short VTl[2][64 * 64];
    __shared__ short Pl[4][32 * 64];

    const int h = blockIdx.y;
    const int t = threadIdx.x, lane = t & 63, w = t >> 6;
    const int c = lane & 15, g = lane >> 4;
    const int qcol = h * DHEAD, kcol = DMODEL + h * DHEAD, vcol = 2 * DMODEL + h * DHEAD;

    // ---- decode chunk ----
    const int xc = blockIdx.x;
    bool causal; int z, NS, q0, kt0, ktn, qt = 0, qb = 0;
    if (xc < 24) {
        causal = false; qb = xc / 3; z = xc - qb * 3; NS = 3;
        q0 = SPOKES + qb * 128; kt0 = z * 16; ktn = 16;
    } else {
        causal = true;
        if (xc < 48)      { const int i = xc - 24; qt = 16 + i / 3; z = i - (i / 3) * 3; NS = 3; }
        else if (xc < 64) { const int i = xc - 48; qt = 8 + (i >> 1); z = i & 1; NS = 2; }
        else              { qt = 71 - xc; z = 0; NS = 1; }
        q0 = qt * 128;
        const int full = 2 * qt + 2, b = full / NS, r = full - b * NS;
        kt0 = z * b + (z < r ? z : r);
        ktn = b + (z < r ? 1 : 0);
    }

    // Q fragments: frag f covers q rows q0 + w*32 + f*16 + c
    bf16x8 qf[2][2];
    #pragma unroll
    for (int f = 0; f < 2; ++f) {
        const short* qrow = qkv + (size_t)(q0 + w * 32 + f * 16 + c) * QKVN + qcol;
        qf[f][0] = *(const bf16x8*)(qrow + g * 8);
        qf[f][1] = *(const bf16x8*)(qrow + 32 + g * 8);
    }

    float m[2] = {-INFINITY, -INFINITY}, l[2] = {0.0f, 0.0f};
    f32x4 acc[2][4] = {};
    bf16x8 vreg[2];

    // ---- staging helpers ----
    auto KDMA = [&](int buf, int kt) {
        const int k0 = kt * 64;
        #pragma unroll
        for (int i = 0; i < 2; ++i) {
            const int ch = i * 256 + t;                 // 16B chunk index
            const int kv = ch >> 3, s = ch & 7;
            const int o = s ^ ((kv & 7) ^ (kv >> 3));   // pre-swizzled source octet
            gload_lds16(qkv + (size_t)(k0 + kv) * QKVN + kcol + o * 8,
                        (char*)Kl[buf] + i * 4096 + w * 1024);
        }
    };
    auto VLOAD = [&](int kt) {
        const int k0 = kt * 64;
        const short* vrow = qkv + (size_t)(k0 + (t >> 2)) * QKVN + vcol;
        vreg[0] = *(const bf16x8*)(vrow + (t & 3) * 8);
        vreg[1] = *(const bf16x8*)(vrow + (t & 3) * 8 + 32);
    };
    auto VWRITE = [&](int buf) {
        const int kv = t >> 2;
        #pragma unroll
        for (int i = 0; i < 2; ++i) {
            const int o = (t & 3) + 4 * i;
            #pragma unroll
            for (int j = 0; j < 8; ++j) {
                const int d = o * 8 + j;
                *(short*)((char*)VTl[buf] + d * 128 + ((kv * 2) ^ swz(d))) = vreg[i][j];
            }
        }
    };

    // ---- prologue: stage tile kt0 into buffer 0 ----
    VLOAD(kt0);
    KDMA(0, kt0);
    VWRITE(0);
    __syncthreads();

    for (int it = 0; it < ktn; ++it) {
        const int kt = kt0 + it;
        const int cur = it & 1, nxt = cur ^ 1;
        const int k0 = kt * 64;

        if (it + 1 < ktn) { VLOAD(kt + 1); KDMA(nxt, kt + 1); }   // async prefetch

        const bool live0 = !causal || (k0 <= q0 + w * 32 + 15);
        const bool live1 = !causal || (k0 <= q0 + w * 32 + 31);

        // ---- S^T = K . Q^T ----
        f32x4 st[2][4];
        #pragma unroll
        for (int mt = 0; mt < 4; ++mt) {
            const int kvr = mt * 16 + c;
            bf16x8 ka = *(const bf16x8*)((const char*)Kl[cur] + kvr * 128 + ((g * 16) ^ swz(kvr)));
            bf16x8 kb = *(const bf16x8*)((const char*)Kl[cur] + kvr * 128 + ((64 + g * 16) ^ swz(kvr)));
            if (live0) {
                f32x4 zz = {0.f, 0.f, 0.f, 0.f};
                zz = __builtin_amdgcn_mfma_f32_16x16x32_bf16(ka, qf[0][0], zz, 0, 0, 0);
                st[0][mt] = __builtin_amdgcn_mfma_f32_16x16x32_bf16(kb, qf[0][1], zz, 0, 0, 0);
            }
            if (live1) {
                f32x4 zz = {0.f, 0.f, 0.f, 0.f};
                zz = __builtin_amdgcn_mfma_f32_16x16x32_bf16(ka, qf[1][0], zz, 0, 0, 0);
                st[1][mt] = __builtin_amdgcn_mfma_f32_16x16x32_bf16(kb, qf[1][1], zz, 0, 0, 0);
            }
        }

        // ---- online softmax per frag; P -> per-wave LDS scratch ----
        #pragma unroll
        for (int f = 0; f < 2; ++f) {
            if (f == 0 ? !live0 : !live1) continue;
            const int qg = q0 + w * 32 + f * 16 + c;
            if (causal && (k0 + 63 > q0 + w * 32 + f * 16)) {
                #pragma unroll
                for (int mt = 0; mt < 4; ++mt)
                    #pragma unroll
                    for (int r = 0; r < 4; ++r)
                        if (k0 + mt * 16 + g * 4 + r > qg) st[f][mt][r] = -INFINITY;
            }
            float tmax = -INFINITY;
            #pragma unroll
            for (int mt = 0; mt < 4; ++mt)
                #pragma unroll
                for (int r = 0; r < 4; ++r) tmax = fmaxf(tmax, st[f][mt][r]);
            tmax = fmaxf(tmax, __shfl_xor(tmax, 16));
            tmax = fmaxf(tmax, __shfl_xor(tmax, 32));
            const float mnew = fmaxf(m[f], tmax);
            const float pfac = __expf(m[f] - mnew);
            float rs = 0.0f;
            const int qrow = f * 16 + c;
            #pragma unroll
            for (int mt = 0; mt < 4; ++mt) {
                bf16x4 pw;
                #pragma unroll
                for (int r = 0; r < 4; ++r) {
                    const float e = __expf(st[f][mt][r] - mnew);
                    rs += e;
                    pw[r] = f2bf(e);
                }
                *(bf16x4*)((char*)Pl[w] + qrow * 128 + ((mt * 32 + g * 8) ^ swz(qrow))) = pw;
            }
            rs += __shfl_xor(rs, 16);
            rs += __shfl_xor(rs, 32);
            l[f] = l[f] * pfac + rs;
            m[f] = mnew;
            #pragma unroll
            for (int dt = 0; dt < 4; ++dt)
                #pragma unroll
                for (int r = 0; r < 4; ++r) acc[f][dt][r] *= pfac;
        }

        // ---- PV: out^T += V^T . P^T ----
        #pragma unroll
        for (int kc = 0; kc < 2; ++kc) {
            bf16x8 vf[4];
            #pragma unroll
            for (int dt = 0; dt < 4; ++dt) {
                const int d = dt * 16 + c;
                vf[dt] = *(const bf16x8*)((const char*)VTl[cur] + d * 128 + ((kc * 64 + g * 16) ^ swz(d)));
            }
            #pragma unroll
            for (int f = 0; f < 2; ++f) {
                if (f == 0 ? !live0 : !live1) continue;
                const int qrow = f * 16 + c;
                bf16x8 pb = *(const bf16x8*)((const char*)Pl[w] + qrow * 128 + ((kc * 64 + g * 16) ^ swz(qrow)));
                #pragma unroll
                for (int dt = 0; dt < 4; ++dt)
                    acc[f][dt] = __builtin_amdgcn_mfma_f32_16x16x32_bf16(vf[dt], pb, acc[f][dt], 0, 0, 0);
            }
        }

        if (it + 1 < ktn) VWRITE(nxt);    // reg data arrived during compute
        __syncthreads();                  // drains KDMA; all readers done with cur
    }

    // ---- epilogue ----
    if (!causal && z == 0) {
        // fold in the self term (split 0 only)
        #pragma unroll
        for (int f = 0; f < 2; ++f) {
            const int qg = q0 + w * 32 + f * 16 + c;
            float ss = 0.0f;
            #pragma unroll
            for (int kc = 0; kc < 2; ++kc) {
                bf16x8 ks = *(const bf16x8*)(qkv + (size_t)qg * QKVN + kcol + kc * 32 + g * 8);
                #pragma unroll
                for (int j = 0; j < 8; ++j) ss += bf2f(qf[f][kc][j]) * bf2f(ks[j]);
            }
            ss += __shfl_xor(ss, 16);
            ss += __shfl_xor(ss, 32);
            const float mnew = fmaxf(m[f], ss);
            const float pf = __expf(m[f] - mnew);
            const float ps = __expf(ss - mnew);
            const short* vrow = qkv + (size_t)qg * QKVN + vcol;
            #pragma unroll
            for (int dt = 0; dt < 4; ++dt) {
                bf16x4 vs = *(const bf16x4*)(vrow + dt * 16 + g * 4);
                #pragma unroll
                for (int r = 0; r < 4; ++r)
                    acc[f][dt][r] = acc[f][dt][r] * pf + ps * bf2f(vs[r]);
            }
            l[f] = l[f] * pf + ps;
            m[f] = mnew;
        }
    }

    if (causal && NS == 1) {
        // direct normalized write
        #pragma unroll
        for (int f = 0; f < 2; ++f) {
            const float inv = 1.0f / l[f];
            short* orow = attn + (size_t)(q0 + w * 32 + f * 16 + c) * DMODEL + qcol;
            #pragma unroll
            for (int dt = 0; dt < 4; ++dt)
                #pragma unroll
                for (int r = 0; r < 4; ++r)
                    orow[dt * 16 + g * 4 + r] = f2bf(acc[f][dt][r] * inv);
        }
    } else if (z == 0) {
        // split-0 partial: unnormalized into attn + (m,l) into pml0
        float* pml0 = causal ? pml0_c : pml0_q;
        const int stride = causal ? 2048 : 1024;
        const int base   = causal ? 1024 : SPOKES;
        #pragma unroll
        for (int f = 0; f < 2; ++f) {
            const int row = q0 + w * 32 + f * 16 + c;
            short* orow = attn + (size_t)row * DMODEL + qcol;
            #pragma unroll
            for (int dt = 0; dt < 4; ++dt)
                #pragma unroll
                for (int r = 0; r < 4; ++r)
                    orow[dt * 16 + g * 4 + r] = f2bf(acc[f][dt][r]);
            if (g == 0) {
                float* p = pml0 + ((size_t)h * stride + (row - base)) * 2;
                p[0] = m[f];
                p[1] = l[f];
            }
        }
    } else {
        // extra-split partial into slot arrays
        const int slot = causal ? (qt < 16 ? qt - 8 : 8 + (qt - 16) * 2 + (z - 1))
                                : qb * 2 + (z - 1);
        short* pacc = causal ? pacc_c : pacc_q;
        float* pml  = causal ? pml_c  : pml_q;
        #pragma unroll
        for (int f = 0; f < 2; ++f) {
            const int rl = w * 32 + f * 16 + c;       // row within 128-row block
            short* prow = pacc + ((size_t)slot * 128 + rl) * DMODEL + qcol;
            #pragma unroll
            for (int dt = 0; dt < 4; ++dt)
                #pragma unroll
                for (int r = 0; r < 4; ++r)
                    prow[dt * 16 + g * 4 + r] = f2bf(acc[f][dt][r]);
            if (g == 0) {
                float* p = pml + ((size_t)(slot * 16 + h) * 128 + rl) * 2;
                p[0] = m[f];
                p[1] = l[f];
            }
        }
    }
}

// ---------------------------------------------------------------------------
// Combine: attn row (split-0, unnormalized, with pml0) + nextra slot partials.
// slot(r, e) = slotBase + (r>>7)*slotMul + e
// ---------------------------------------------------------------------------
__global__ __launch_bounds__(256) void attn_combine(
    short* __restrict__ attn, const float* __restrict__ pml0,
    const short* __restrict__ pacc, const float* __restrict__ pml,
    int rowbase, int pml0_stride, int pml0_off,
    int slotBase, int slotMul, int nextra)
{
    const int i = blockIdx.x * 256 + threadIdx.x;   // nrows * NH * 8 threads
    const int r = i >> 7;
    const int h = (i >> 3) & 15;
    const int o = i & 7;

    const float* p0 = pml0 + ((size_t)h * pml0_stride + pml0_off + r) * 2;
    const float m0 = p0[0], l0 = p0[1];
    float M = m0;
    float me[2], le[2];
    for (int e = 0; e < nextra; ++e) {
        const int slot = slotBase + (r >> 7) * slotMul + e;
        const float* p = pml + ((size_t)(slot * 16 + h) * 128 + (r & 127)) * 2;
        me[e] = p[0]; le[e] = p[1];
        M = fmaxf(M, me[e]);
    }
    const float w0 = __expf(m0 - M);
    float L = w0 * l0;
    float we[2];
    for (int e = 0; e < nextra; ++e) { we[e] = __expf(me[e] - M); L += we[e] * le[e]; }

    short* arow = attn + (size_t)(rowbase + r) * DMODEL + h * 64 + o * 8;
    bf16x8 a0 = *(const bf16x8*)arow;
    float outv[8];
    #pragma unroll
    for (int j = 0; j < 8; ++j) outv[j] = w0 * bf2f(a0[j]);
    for (int e = 0; e < nextra; ++e) {
        const int slot = slotBase + (r >> 7) * slotMul + e;
        bf16x8 a = *(const bf16x8*)(pacc + ((size_t)slot * 128 + (r & 127)) * DMODEL + h * 64 + o * 8);
        #pragma unroll
        for (int j = 0; j < 8; ++j) outv[j] += we[e] * bf2f(a[j]);
    }
    const float inv = 1.0f / L;
    bf16x8 res;
    #pragma unroll
    for (int j = 0; j < 8; ++j) res[j] = f2bf(outv[j] * inv);
    *(bf16x8*)arow = res;
}

// ---------------------------------------------------------------------------
extern "C" void kernel_launch(void* const* d_in, const int* in_sizes, int n_in,
                              void* d_out, int out_size, void* d_ws, size_t ws_size,
                              hipStream_t stream)
{
    const float* x      = (const float*)d_in[0];
    const float* pos    = (const float*)d_in[1];
    const float* qkv_w  = (const float*)d_in[2];
    const float* out_w  = (const float*)d_in[3];
    const float* scale  = (const float*)d_in[4];
    const float* freqs  = (const float*)d_in[5];
    float*       out    = (float*)d_out;

    const size_t MB = 1024 * 1024;
    char* ws = (char*)d_ws;
    short* qkv_bf  = (short*)(ws);                       // [0,24MB)  qkv (live)
    short* x_bf    = (short*)(ws + 24 * MB);             // [24,32)   x -> attn (alias)
    short* wqkv_bf = (short*)(ws + 32 * MB);             // [32,38)   qkv_w -> query partials
    short* wout_bf = (short*)(ws + 38 * MB);             // [38,40)   out_w (live)
    short* pacc_c  = (short*)(ws + 40 * MB);             // [40,46)   24 slots x 128 x 1024 bf16
    float* pml_c   = (float*)(ws + 46 * MB);             // 393216 B
    float* pml0_c  = (float*)(ws + 46 * MB + 393216);    // 262144 B  (ends 46.625MB)
    short* attn_bf = x_bf;                               // alias (x dead after gemm1)
    short* pacc_q  = wqkv_bf;                            // 16 slots x 128 x 1024 bf16 (4.19MB)
    float* pml_q   = (float*)((char*)wqkv_bf + 4194304); // 262144 B
    float* pml0_q  = (float*)((char*)wqkv_bf + 4456448); // 131072 B (ends 36.375MB)

    const dim3 blk(256);

    cvt_f32_bf16<<<dim3(SEQL * DMODEL / 8 / 256), blk, 0, stream>>>(x, x_bf, SEQL * DMODEL / 8);
    cvt_f32_bf16<<<dim3(QKVN * DMODEL / 8 / 256), blk, 0, stream>>>(qkv_w, wqkv_bf, QKVN * DMODEL / 8);
    cvt_f32_bf16<<<dim3(DMODEL * DMODEL / 8 / 256), blk, 0, stream>>>(out_w, wout_bf, DMODEL * DMODEL / 8);

    // 1) qkv = x @ qkv_w^T  (bf16 in, bf16 out)
    gemm_bf16<true><<<dim3(QKVN / 128, SEQL / 128), blk, 0, stream>>>(
        x_bf, wqkv_bf, qkv_bf, DMODEL, QKVN);

    // 2) cos-scale + axial rope on q,k (in place, bf16)
    transform_qk<<<dim3(SEQL * NH / 4), blk, 0, stream>>>(qkv_bf, pos, scale, freqs);

    // 3) fused attention, uniform <=16-tile chunks (causal + query)
    attn_fused<<<dim3(72, NH), blk, 0, stream>>>(
        qkv_bf, attn_bf, pacc_c, pml_c, pml0_c, pacc_q, pml_q, pml0_q);

    // 4) combines: causal qt8..15 (1 extra), qt16..23 (2 extra), query (2 extra)
    attn_combine<<<dim3(512), blk, 0, stream>>>(attn_bf, pml0_c, pacc_c, pml_c,
                                                1024, 2048, 0,    0, 1, 1);
    attn_combine<<<dim3(512), blk, 0, stream>>>(attn_bf, pml0_c, pacc_c, pml_c,
                                                2048, 2048, 1024, 8, 2, 2);
    attn_combine<<<dim3(512), blk, 0, stream>>>(attn_bf, pml0_q, pacc_q, pml_q,
                                                SPOKES, 1024, 0,  0, 2, 2);

    // 5) out = attn @ out_w^T  (bf16 in, f32 out)
    gemm_bf16<false><<<dim3(DMODEL / 128, SEQL / 128), blk, 0, stream>>>(
        attn_bf, wout_bf, out, DMODEL, DMODEL);
}

// Round 7
// 225.998 us; speedup vs baseline: 9.5835x; 1.0341x over previous
//
#include <hip/hip_runtime.h>
#include <math.h>

#define SEQL   4096
#define DMODEL 1024
#define NH     16
#define DHEAD  64
#define SPOKES 3072
#define NQUERY (SEQL - SPOKES)     // 1024
#define QKVN   (3 * DMODEL)        // 3072

typedef short bf16x8 __attribute__((ext_vector_type(8)));
typedef short bf16x4 __attribute__((ext_vector_type(4)));
typedef float f32x4  __attribute__((ext_vector_type(4)));

__device__ __forceinline__ short f2bf(float f) {
    unsigned u = __builtin_bit_cast(unsigned, f);
    u += 0x7fffu + ((u >> 16) & 1u);     // RNE
    return (short)(u >> 16);
}
__device__ __forceinline__ float bf2f(short s) {
    unsigned u = ((unsigned)(unsigned short)s) << 16;
    return __builtin_bit_cast(float, u);
}
// packed f32x2 -> bf16x2 (RNE), low half = lo
__device__ __forceinline__ unsigned cvt_pk_bf16(float lo, float hi) {
    unsigned u;
    asm("v_cvt_pk_bf16_f32 %0, %1, %2" : "=v"(u) : "v"(lo), "v"(hi));
    return u;
}
// XOR swizzle on byte bits 4..6, keyed by LDS row (rows are 128B).
__device__ __forceinline__ int swz(int row) { return ((row & 7) ^ (row >> 3)) << 4; }

// async global->LDS, 16B per lane; LDS dest = wave-uniform base + lane*16
__device__ __forceinline__ void gload_lds16(const void* g, void* l) {
    __builtin_amdgcn_global_load_lds(
        (const __attribute__((address_space(1))) unsigned int*)g,
        (__attribute__((address_space(3))) unsigned int*)l,
        16, 0, 0);
}

// ---------------------------------------------------------------------------
// f32 -> bf16 conversion, 8 elems/thread
// ---------------------------------------------------------------------------
__global__ __launch_bounds__(256) void cvt_f32_bf16(
    const float* __restrict__ in, short* __restrict__ out, int n8)
{
    const int i = blockIdx.x * 256 + threadIdx.x;
    if (i >= n8) return;
    float4 a = ((const float4*)in)[i * 2];
    float4 b = ((const float4*)in)[i * 2 + 1];
    bf16x8 v;
    v[0] = f2bf(a.x); v[1] = f2bf(a.y); v[2] = f2bf(a.z); v[3] = f2bf(a.w);
    v[4] = f2bf(b.x); v[5] = f2bf(b.y); v[6] = f2bf(b.z); v[7] = f2bf(b.w);
    ((bf16x8*)out)[i] = v;
}

// ---------------------------------------------------------------------------
// bf16 MFMA GEMM (unchanged): C = A * B^T, 128x128 tile, BK=64.
// ---------------------------------------------------------------------------
template<bool BF16OUT>
__global__ __launch_bounds__(256) void gemm_bf16(
    const short* __restrict__ A, const short* __restrict__ B, void* __restrict__ Cv,
    int K, int ldc)
{
    __shared__ short As[128 * 64];
    __shared__ short Bs[128 * 64];

    const int t = threadIdx.x;
    const int lane = t & 63, w = t >> 6;
    const int c = lane & 15, g = lane >> 4;
    const int wr = w >> 1, wc = w & 1;
    const int m0 = blockIdx.y * 128, n0 = blockIdx.x * 128;

    f32x4 acc[4][4] = {};

    for (int k0 = 0; k0 < K; k0 += 64) {
        __syncthreads();
        #pragma unroll
        for (int i = 0; i < 4; ++i) {
            const int chunk = (w * 4 + i) * 64 + lane;
            const int row = chunk >> 3, cc = chunk & 7;
            gload_lds16(A + (size_t)(m0 + row) * K + k0 + cc * 8,
                        As + (size_t)(w * 4 + i) * 512);
            gload_lds16(B + (size_t)(n0 + row) * K + k0 + cc * 8,
                        Bs + (size_t)(w * 4 + i) * 512);
        }
        __syncthreads();

        #pragma unroll
        for (int kk = 0; kk < 2; ++kk) {
            bf16x8 af[4], bf[4];
            #pragma unroll
            for (int i = 0; i < 4; ++i)
                af[i] = *(const bf16x8*)(As + (wr * 64 + i * 16 + c) * 64 + kk * 32 + g * 8);
            #pragma unroll
            for (int j = 0; j < 4; ++j)
                bf[j] = *(const bf16x8*)(Bs + (wc * 64 + j * 16 + c) * 64 + kk * 32 + g * 8);
            #pragma unroll
            for (int i = 0; i < 4; ++i)
                #pragma unroll
                for (int j = 0; j < 4; ++j)
                    acc[i][j] = __builtin_amdgcn_mfma_f32_16x16x32_bf16(af[i], bf[j], acc[i][j], 0, 0, 0);
        }
    }

    #pragma unroll
    for (int i = 0; i < 4; ++i)
        #pragma unroll
        for (int r = 0; r < 4; ++r) {
            const int row = m0 + wr * 64 + i * 16 + g * 4 + r;
            #pragma unroll
            for (int j = 0; j < 4; ++j) {
                const int col = n0 + wc * 64 + j * 16 + c;
                const float v = acc[i][j][r];
                if (BF16OUT) ((short*)Cv)[(size_t)row * ldc + col] = f2bf(v);
                else         ((float*)Cv)[(size_t)row * ldc + col] = v;
            }
        }
}

// ---------------------------------------------------------------------------
// In-place cos-scale + axial RoPE on bf16 q and k (unchanged).
// ---------------------------------------------------------------------------
__global__ __launch_bounds__(256) void transform_qk(
    short* __restrict__ qkv, const float* __restrict__ pos,
    const float* __restrict__ scale, const float* __restrict__ freqs)
{
    const int w    = threadIdx.x >> 6;
    const int lane = threadIdx.x & 63;
    const int rid  = blockIdx.x * 4 + w;
    const int l    = rid >> 4;
    const int h    = rid & 15;

    short* qp = qkv + (size_t)l * QKVN + h * DHEAD;
    short* kp = qp + DMODEL;

    float q = bf2f(qp[lane]);
    float k = bf2f(kp[lane]);

    float sq = q * q, sk = k * k;
    #pragma unroll
    for (int o = 32; o > 0; o >>= 1) {
        sq += __shfl_xor(sq, o);
        sk += __shfl_xor(sk, o);
    }
    const float ss = sqrtf(fabsf(scale[h]) + 1e-8f);
    q *= ss * rsqrtf(sq + 1e-8f);
    k *= ss * rsqrtf(sk + 1e-8f);

    const int   j  = lane & 31;
    const float p  = pos[l * 2 + (j < 16 ? 1 : 0)];
    const float fj = (j < 16) ? freqs[256 + h * 16 + j] : freqs[h * 16 + (j - 16)];
    const float th = (p * 2.0f - 1.0f) * fj;
    const float cs = cosf(th), sn = sinf(th);

    const float qo = __shfl_xor(q, 32);
    const float ko = __shfl_xor(k, 32);
    const float qr = (lane < 32) ? q * cs - qo * sn : q * cs + qo * sn;
    const float kr = (lane < 32) ? k * cs - ko * sn : k * cs + ko * sn;

    qp[lane] = f2bf(qr);
    kp[lane] = f2bf(kr);
}

// ---------------------------------------------------------------------------
// Fused flash attention, uniform-work chunks (<=16 kv-tiles per block).
// grid = (72, 16): x 0..23 query chunks (8 qb x 3 splits), 24..47 causal
// qt16..23 x3, 48..63 causal qt8..15 x2, 64..71 causal qt7..0 direct.
// This round: cvt_pk P-pack, defer-max (THR=8), pair-kv V staging (b32 writes).
// ---------------------------------------------------------------------------
__global__ __launch_bounds__(256) void attn_fused(
    const short* __restrict__ qkv, short* __restrict__ attn,
    short* __restrict__ pacc_c, float* __restrict__ pml_c, float* __restrict__ pml0_c,
    short* __restrict__ pacc_q, float* __restrict__ pml_q, float* __restrict__ pml0_q)
{
    __shared__ short Kl[2][64 * 64];
    __shared__ short VTl[2][64 * 64];
    __shared__ short Pl[4][32 * 64];

    const int h = blockIdx.y;
    const int t = threadIdx.x, lane = t & 63, w = t >> 6;
    const int c = lane & 15, g = lane >> 4;
    const int qcol = h * DHEAD, kcol = DMODEL + h * DHEAD, vcol = 2 * DMODEL + h * DHEAD;

    // ---- decode chunk ----
    const int xc = blockIdx.x;
    bool causal; int z, NS, q0, kt0, ktn, qt = 0, qb = 0;
    if (xc < 24) {
        causal = false; qb = xc / 3; z = xc - qb * 3; NS = 3;
        q0 = SPOKES + qb * 128; kt0 = z * 16; ktn = 16;
    } else {
        causal = true;
        if (xc < 48)      { const int i = xc - 24; qt = 16 + i / 3; z = i - (i / 3) * 3; NS = 3; }
        else if (xc < 64) { const int i = xc - 48; qt = 8 + (i >> 1); z = i & 1; NS = 2; }
        else              { qt = 71 - xc; z = 0; NS = 1; }
        q0 = qt * 128;
        const int full = 2 * qt + 2, b = full / NS, r = full - b * NS;
        kt0 = z * b + (z < r ? z : r);
        ktn = b + (z < r ? 1 : 0);
    }

    // Q fragments: frag f covers q rows q0 + w*32 + f*16 + c
    bf16x8 qf[2][2];
    #pragma unroll
    for (int f = 0; f < 2; ++f) {
        const short* qrow = qkv + (size_t)(q0 + w * 32 + f * 16 + c) * QKVN + qcol;
        qf[f][0] = *(const bf16x8*)(qrow + g * 8);
        qf[f][1] = *(const bf16x8*)(qrow + 32 + g * 8);
    }

    float m[2] = {-INFINITY, -INFINITY}, l[2] = {0.0f, 0.0f};
    f32x4 acc[2][4] = {};
    bf16x8 vregA, vregB;

    // ---- staging helpers ----
    auto KDMA = [&](int buf, int kt) {
        const int k0 = kt * 64;
        #pragma unroll
        for (int i = 0; i < 2; ++i) {
            const int ch = i * 256 + t;                 // 16B chunk index
            const int kv = ch >> 3, s = ch & 7;
            const int o = s ^ ((kv & 7) ^ (kv >> 3));   // pre-swizzled source octet
            gload_lds16(qkv + (size_t)(k0 + kv) * QKVN + kcol + o * 8,
                        (char*)Kl[buf] + i * 4096 + w * 1024);
        }
    };
    // thread t owns kv pair {2*(t>>3), 2*(t>>3)+1} x d-octet (t&7)
    auto VLOAD = [&](int kt) {
        const int k0 = kt * 64;
        const short* v0 = qkv + (size_t)(k0 + 2 * (t >> 3)) * QKVN + vcol + (t & 7) * 8;
        vregA = *(const bf16x8*)v0;
        vregB = *(const bf16x8*)(v0 + QKVN);
    };
    auto VWRITE = [&](int buf) {
        const int p2 = t >> 3, oc = t & 7;
        #pragma unroll
        for (int j = 0; j < 8; ++j) {
            const int d = oc * 8 + j;
            const unsigned u = ((unsigned)(unsigned short)vregA[j]) |
                               (((unsigned)(unsigned short)vregB[j]) << 16);
            *(unsigned*)((char*)VTl[buf] + d * 128 + ((4 * p2) ^ swz(d))) = u;
        }
    };

    // ---- prologue: stage tile kt0 into buffer 0 ----
    VLOAD(kt0);
    KDMA(0, kt0);
    VWRITE(0);
    __syncthreads();

    for (int it = 0; it < ktn; ++it) {
        const int kt = kt0 + it;
        const int cur = it & 1, nxt = cur ^ 1;
        const int k0 = kt * 64;

        if (it + 1 < ktn) { VLOAD(kt + 1); KDMA(nxt, kt + 1); }   // async prefetch

        const bool live0 = !causal || (k0 <= q0 + w * 32 + 15);
        const bool live1 = !causal || (k0 <= q0 + w * 32 + 31);

        // ---- S^T = K . Q^T ----
        f32x4 st[2][4];
        #pragma unroll
        for (int mt = 0; mt < 4; ++mt) {
            const int kvr = mt * 16 + c;
            bf16x8 ka = *(const bf16x8*)((const char*)Kl[cur] + kvr * 128 + ((g * 16) ^ swz(kvr)));
            bf16x8 kb = *(const bf16x8*)((const char*)Kl[cur] + kvr * 128 + ((64 + g * 16) ^ swz(kvr)));
            if (live0) {
                f32x4 zz = {0.f, 0.f, 0.f, 0.f};
                zz = __builtin_amdgcn_mfma_f32_16x16x32_bf16(ka, qf[0][0], zz, 0, 0, 0);
                st[0][mt] = __builtin_amdgcn_mfma_f32_16x16x32_bf16(kb, qf[0][1], zz, 0, 0, 0);
            }
            if (live1) {
                f32x4 zz = {0.f, 0.f, 0.f, 0.f};
                zz = __builtin_amdgcn_mfma_f32_16x16x32_bf16(ka, qf[1][0], zz, 0, 0, 0);
                st[1][mt] = __builtin_amdgcn_mfma_f32_16x16x32_bf16(kb, qf[1][1], zz, 0, 0, 0);
            }
        }

        // ---- online softmax per frag (defer-max); P -> per-wave LDS scratch ----
        #pragma unroll
        for (int f = 0; f < 2; ++f) {
            if (f == 0 ? !live0 : !live1) continue;
            const int qg = q0 + w * 32 + f * 16 + c;
            if (causal && (k0 + 63 > q0 + w * 32 + f * 16)) {
                #pragma unroll
                for (int mt = 0; mt < 4; ++mt)
                    #pragma unroll
                    for (int r = 0; r < 4; ++r)
                        if (k0 + mt * 16 + g * 4 + r > qg) st[f][mt][r] = -INFINITY;
            }
            float tmax = -INFINITY;
            #pragma unroll
            for (int mt = 0; mt < 4; ++mt)
                #pragma unroll
                for (int r = 0; r < 4; ++r) tmax = fmaxf(tmax, st[f][mt][r]);
            tmax = fmaxf(tmax, __shfl_xor(tmax, 16));
            tmax = fmaxf(tmax, __shfl_xor(tmax, 32));
            if (__any(tmax > m[f] + 8.0f)) {          // rescale only on real max growth
                const float mnew = fmaxf(m[f], tmax); // per-lane (per q-row), vote uniform
                const float pfac = __expf(m[f] - mnew);
                l[f] *= pfac;
                #pragma unroll
                for (int dt = 0; dt < 4; ++dt)
                    #pragma unroll
                    for (int r = 0; r < 4; ++r) acc[f][dt][r] *= pfac;
                m[f] = mnew;
            }
            const float mref = m[f];
            float rs = 0.0f;
            const int qrow = f * 16 + c;
            #pragma unroll
            for (int mt = 0; mt < 4; ++mt) {
                const float e0 = __expf(st[f][mt][0] - mref);
                const float e1 = __expf(st[f][mt][1] - mref);
                const float e2 = __expf(st[f][mt][2] - mref);
                const float e3 = __expf(st[f][mt][3] - mref);
                rs += (e0 + e1) + (e2 + e3);
                uint2 u;
                u.x = cvt_pk_bf16(e0, e1);
                u.y = cvt_pk_bf16(e2, e3);
                *(uint2*)((char*)Pl[w] + qrow * 128 + ((mt * 32 + g * 8) ^ swz(qrow))) = u;
            }
            rs += __shfl_xor(rs, 16);
            rs += __shfl_xor(rs, 32);
            l[f] += rs;
        }

        // ---- PV: out^T += V^T . P^T ----
        #pragma unroll
        for (int kc = 0; kc < 2; ++kc) {
            bf16x8 vf[4];
            #pragma unroll
            for (int dt = 0; dt < 4; ++dt) {
                const int d = dt * 16 + c;
                vf[dt] = *(const bf16x8*)((const char*)VTl[cur] + d * 128 + ((kc * 64 + g * 16) ^ swz(d)));
            }
            #pragma unroll
            for (int f = 0; f < 2; ++f) {
                if (f == 0 ? !live0 : !live1) continue;
                const int qrow = f * 16 + c;
                bf16x8 pb = *(const bf16x8*)((const char*)Pl[w] + qrow * 128 + ((kc * 64 + g * 16) ^ swz(qrow)));
                #pragma unroll
                for (int dt = 0; dt < 4; ++dt)
                    acc[f][dt] = __builtin_amdgcn_mfma_f32_16x16x32_bf16(vf[dt], pb, acc[f][dt], 0, 0, 0);
            }
        }

        if (it + 1 < ktn) VWRITE(nxt);    // reg data arrived during compute
        __syncthreads();                  // drains KDMA; all readers done with cur
    }

    // ---- epilogue ----
    if (!causal && z == 0) {
        // fold in the self term (split 0 only)
        #pragma unroll
        for (int f = 0; f < 2; ++f) {
            const int qg = q0 + w * 32 + f * 16 + c;
            float ss = 0.0f;
            #pragma unroll
            for (int kc = 0; kc < 2; ++kc) {
                bf16x8 ks = *(const bf16x8*)(qkv + (size_t)qg * QKVN + kcol + kc * 32 + g * 8);
                #pragma unroll
                for (int j = 0; j < 8; ++j) ss += bf2f(qf[f][kc][j]) * bf2f(ks[j]);
            }
            ss += __shfl_xor(ss, 16);
            ss += __shfl_xor(ss, 32);
            const float mnew = fmaxf(m[f], ss);
            const float pf = __expf(m[f] - mnew);
            const float ps = __expf(ss - mnew);
            const short* vrow = qkv + (size_t)qg * QKVN + vcol;
            #pragma unroll
            for (int dt = 0; dt < 4; ++dt) {
                bf16x4 vs = *(const bf16x4*)(vrow + dt * 16 + g * 4);
                #pragma unroll
                for (int r = 0; r < 4; ++r)
                    acc[f][dt][r] = acc[f][dt][r] * pf + ps * bf2f(vs[r]);
            }
            l[f] = l[f] * pf + ps;
            m[f] = mnew;
        }
    }

    if (causal && NS == 1) {
        // direct normalized write
        #pragma unroll
        for (int f = 0; f < 2; ++f) {
            const float inv = 1.0f / l[f];
            short* orow = attn + (size_t)(q0 + w * 32 + f * 16 + c) * DMODEL + qcol;
            #pragma unroll
            for (int dt = 0; dt < 4; ++dt)
                #pragma unroll
                for (int r = 0; r < 4; ++r)
                    orow[dt * 16 + g * 4 + r] = f2bf(acc[f][dt][r] * inv);
        }
    } else if (z == 0) {
        // split-0 partial: unnormalized into attn + (m,l) into pml0
        float* pml0 = causal ? pml0_c : pml0_q;
        const int stride = causal ? 2048 : 1024;
        const int base   = causal ? 1024 : SPOKES;
        #pragma unroll
        for (int f = 0; f < 2; ++f) {
            const int row = q0 + w * 32 + f * 16 + c;
            short* orow = attn + (size_t)row * DMODEL + qcol;
            #pragma unroll
            for (int dt = 0; dt < 4; ++dt)
                #pragma unroll
                for (int r = 0; r < 4; ++r)
                    orow[dt * 16 + g * 4 + r] = f2bf(acc[f][dt][r]);
            if (g == 0) {
                float* p = pml0 + ((size_t)h * stride + (row - base)) * 2;
                p[0] = m[f];
                p[1] = l[f];
            }
        }
    } else {
        // extra-split partial into slot arrays
        const int slot = causal ? (qt < 16 ? qt - 8 : 8 + (qt - 16) * 2 + (z - 1))
                                : qb * 2 + (z - 1);
        short* pacc = causal ? pacc_c : pacc_q;
        float* pml  = causal ? pml_c  : pml_q;
        #pragma unroll
        for (int f = 0; f < 2; ++f) {
            const int rl = w * 32 + f * 16 + c;       // row within 128-row block
            short* prow = pacc + ((size_t)slot * 128 + rl) * DMODEL + qcol;
            #pragma unroll
            for (int dt = 0; dt < 4; ++dt)
                #pragma unroll
                for (int r = 0; r < 4; ++r)
                    prow[dt * 16 + g * 4 + r] = f2bf(acc[f][dt][r]);
            if (g == 0) {
                float* p = pml + ((size_t)(slot * 16 + h) * 128 + rl) * 2;
                p[0] = m[f];
                p[1] = l[f];
            }
        }
    }
}

// ---------------------------------------------------------------------------
// Combine: attn row (split-0, unnormalized, with pml0) + nextra slot partials.
// slot(r, e) = slotBase + (r>>7)*slotMul + e
// ---------------------------------------------------------------------------
__global__ __launch_bounds__(256) void attn_combine(
    short* __restrict__ attn, const float* __restrict__ pml0,
    const short* __restrict__ pacc, const float* __restrict__ pml,
    int rowbase, int pml0_stride, int pml0_off,
    int slotBase, int slotMul, int nextra)
{
    const int i = blockIdx.x * 256 + threadIdx.x;   // nrows * NH * 8 threads
    const int r = i >> 7;
    const int h = (i >> 3) & 15;
    const int o = i & 7;

    const float* p0 = pml0 + ((size_t)h * pml0_stride + pml0_off + r) * 2;
    const float m0 = p0[0], l0 = p0[1];
    float M = m0;
    float me[2], le[2];
    for (int e = 0; e < nextra; ++e) {
        const int slot = slotBase + (r >> 7) * slotMul + e;
        const float* p = pml + ((size_t)(slot * 16 + h) * 128 + (r & 127)) * 2;
        me[e] = p[0]; le[e] = p[1];
        M = fmaxf(M, me[e]);
    }
    const float w0 = __expf(m0 - M);
    float L = w0 * l0;
    float we[2];
    for (int e = 0; e < nextra; ++e) { we[e] = __expf(me[e] - M); L += we[e] * le[e]; }

    short* arow = attn + (size_t)(rowbase + r) * DMODEL + h * 64 + o * 8;
    bf16x8 a0 = *(const bf16x8*)arow;
    float outv[8];
    #pragma unroll
    for (int j = 0; j < 8; ++j) outv[j] = w0 * bf2f(a0[j]);
    for (int e = 0; e < nextra; ++e) {
        const int slot = slotBase + (r >> 7) * slotMul + e;
        bf16x8 a = *(const bf16x8*)(pacc + ((size_t)slot * 128 + (r & 127)) * DMODEL + h * 64 + o * 8);
        #pragma unroll
        for (int j = 0; j < 8; ++j) outv[j] += we[e] * bf2f(a[j]);
    }
    const float inv = 1.0f / L;
    bf16x8 res;
    #pragma unroll
    for (int j = 0; j < 8; ++j) res[j] = f2bf(outv[j] * inv);
    *(bf16x8*)arow = res;
}

// ---------------------------------------------------------------------------
extern "C" void kernel_launch(void* const* d_in, const int* in_sizes, int n_in,
                              void* d_out, int out_size, void* d_ws, size_t ws_size,
                              hipStream_t stream)
{
    const float* x      = (const float*)d_in[0];
    const float* pos    = (const float*)d_in[1];
    const float* qkv_w  = (const float*)d_in[2];
    const float* out_w  = (const float*)d_in[3];
    const float* scale  = (const float*)d_in[4];
    const float* freqs  = (const float*)d_in[5];
    float*       out    = (float*)d_out;

    const size_t MB = 1024 * 1024;
    char* ws = (char*)d_ws;
    short* qkv_bf  = (short*)(ws);                       // [0,24MB)  qkv (live)
    short* x_bf    = (short*)(ws + 24 * MB);             // [24,32)   x -> attn (alias)
    short* wqkv_bf = (short*)(ws + 32 * MB);             // [32,38)   qkv_w -> query partials
    short* wout_bf = (short*)(ws + 38 * MB);             // [38,40)   out_w (live)
    short* pacc_c  = (short*)(ws + 40 * MB);             // [40,46)   24 slots x 128 x 1024 bf16
    float* pml_c   = (float*)(ws + 46 * MB);             // 393216 B
    float* pml0_c  = (float*)(ws + 46 * MB + 393216);    // 262144 B  (ends 46.625MB)
    short* attn_bf = x_bf;                               // alias (x dead after gemm1)
    short* pacc_q  = wqkv_bf;                            // 16 slots x 128 x 1024 bf16 (4.19MB)
    float* pml_q   = (float*)((char*)wqkv_bf + 4194304); // 262144 B
    float* pml0_q  = (float*)((char*)wqkv_bf + 4456448); // 131072 B (ends 36.375MB)

    const dim3 blk(256);

    cvt_f32_bf16<<<dim3(SEQL * DMODEL / 8 / 256), blk, 0, stream>>>(x, x_bf, SEQL * DMODEL / 8);
    cvt_f32_bf16<<<dim3(QKVN * DMODEL / 8 / 256), blk, 0, stream>>>(qkv_w, wqkv_bf, QKVN * DMODEL / 8);
    cvt_f32_bf16<<<dim3(DMODEL * DMODEL / 8 / 256), blk, 0, stream>>>(out_w, wout_bf, DMODEL * DMODEL / 8);

    // 1) qkv = x @ qkv_w^T  (bf16 in, bf16 out)
    gemm_bf16<true><<<dim3(QKVN / 128, SEQL / 128), blk, 0, stream>>>(
        x_bf, wqkv_bf, qkv_bf, DMODEL, QKVN);

    // 2) cos-scale + axial rope on q,k (in place, bf16)
    transform_qk<<<dim3(SEQL * NH / 4), blk, 0, stream>>>(qkv_bf, pos, scale, freqs);

    // 3) fused attention, uniform <=16-tile chunks (causal + query)
    attn_fused<<<dim3(72, NH), blk, 0, stream>>>(
        qkv_bf, attn_bf, pacc_c, pml_c, pml0_c, pacc_q, pml_q, pml0_q);

    // 4) combines: causal qt8..15 (1 extra), qt16..23 (2 extra), query (2 extra)
    attn_combine<<<dim3(512), blk, 0, stream>>>(attn_bf, pml0_c, pacc_c, pml_c,
                                                1024, 2048, 0,    0, 1, 1);
    attn_combine<<<dim3(512), blk, 0, stream>>>(attn_bf, pml0_c, pacc_c, pml_c,
                                                2048, 2048, 1024, 8, 2, 2);
    attn_combine<<<dim3(512), blk, 0, stream>>>(attn_bf, pml0_q, pacc_q, pml_q,
                                                SPOKES, 1024, 0,  0, 2, 2);

    // 5) out = attn @ out_w^T  (bf16 in, f32 out)
    gemm_bf16<false><<<dim3(DMODEL / 128, SEQL / 128), blk, 0, stream>>>(
        attn_bf, wout_bf, out, DMODEL, DMODEL);
}

// Round 8
// 203.444 us; speedup vs baseline: 10.6459x; 1.1109x over previous
//
#include <hip/hip_runtime.h>
#include <math.h>

#define SEQL   4096
#define DMODEL 1024
#define NH     16
#define DHEAD  64
#define SPOKES 3072
#define NQUERY (SEQL - SPOKES)     // 1024
#define QKVN   (3 * DMODEL)        // 3072

typedef short bf16x8 __attribute__((ext_vector_type(8)));
typedef short bf16x4 __attribute__((ext_vector_type(4)));
typedef float f32x4  __attribute__((ext_vector_type(4)));

__device__ __forceinline__ short f2bf(float f) {
    unsigned u = __builtin_bit_cast(unsigned, f);
    u += 0x7fffu + ((u >> 16) & 1u);     // RNE
    return (short)(u >> 16);
}
__device__ __forceinline__ float bf2f(short s) {
    unsigned u = ((unsigned)(unsigned short)s) << 16;
    return __builtin_bit_cast(float, u);
}
// packed f32x2 -> bf16x2 (RNE), low half = lo
__device__ __forceinline__ unsigned cvt_pk_bf16(float lo, float hi) {
    unsigned u;
    asm("v_cvt_pk_bf16_f32 %0, %1, %2" : "=v"(u) : "v"(lo), "v"(hi));
    return u;
}
// XOR swizzle on byte bits 4..6, keyed by LDS row (rows are 128B).
__device__ __forceinline__ int swz(int row) { return ((row & 7) ^ (row >> 3)) << 4; }

// async global->LDS, 16B per lane; LDS dest = wave-uniform base + lane*16
__device__ __forceinline__ void gload_lds16(const void* g, void* l) {
    __builtin_amdgcn_global_load_lds(
        (const __attribute__((address_space(1))) unsigned int*)g,
        (__attribute__((address_space(3))) unsigned int*)l,
        16, 0, 0);
}

// ---------------------------------------------------------------------------
// f32 -> bf16 conversion, 8 elems/thread
// ---------------------------------------------------------------------------
__global__ __launch_bounds__(256) void cvt_f32_bf16(
    const float* __restrict__ in, short* __restrict__ out, int n8)
{
    const int i = blockIdx.x * 256 + threadIdx.x;
    if (i >= n8) return;
    float4 a = ((const float4*)in)[i * 2];
    float4 b = ((const float4*)in)[i * 2 + 1];
    bf16x8 v;
    v[0] = f2bf(a.x); v[1] = f2bf(a.y); v[2] = f2bf(a.z); v[3] = f2bf(a.w);
    v[4] = f2bf(b.x); v[5] = f2bf(b.y); v[6] = f2bf(b.z); v[7] = f2bf(b.w);
    ((bf16x8*)out)[i] = v;
}

// ---------------------------------------------------------------------------
// bf16 MFMA GEMM (unchanged): C = A * B^T, 128x128 tile, BK=64.
// ---------------------------------------------------------------------------
template<bool BF16OUT>
__global__ __launch_bounds__(256) void gemm_bf16(
    const short* __restrict__ A, const short* __restrict__ B, void* __restrict__ Cv,
    int K, int ldc)
{
    __shared__ short As[128 * 64];
    __shared__ short Bs[128 * 64];

    const int t = threadIdx.x;
    const int lane = t & 63, w = t >> 6;
    const int c = lane & 15, g = lane >> 4;
    const int wr = w >> 1, wc = w & 1;
    const int m0 = blockIdx.y * 128, n0 = blockIdx.x * 128;

    f32x4 acc[4][4] = {};

    for (int k0 = 0; k0 < K; k0 += 64) {
        __syncthreads();
        #pragma unroll
        for (int i = 0; i < 4; ++i) {
            const int chunk = (w * 4 + i) * 64 + lane;
            const int row = chunk >> 3, cc = chunk & 7;
            gload_lds16(A + (size_t)(m0 + row) * K + k0 + cc * 8,
                        As + (size_t)(w * 4 + i) * 512);
            gload_lds16(B + (size_t)(n0 + row) * K + k0 + cc * 8,
                        Bs + (size_t)(w * 4 + i) * 512);
        }
        __syncthreads();

        #pragma unroll
        for (int kk = 0; kk < 2; ++kk) {
            bf16x8 af[4], bf[4];
            #pragma unroll
            for (int i = 0; i < 4; ++i)
                af[i] = *(const bf16x8*)(As + (wr * 64 + i * 16 + c) * 64 + kk * 32 + g * 8);
            #pragma unroll
            for (int j = 0; j < 4; ++j)
                bf[j] = *(const bf16x8*)(Bs + (wc * 64 + j * 16 + c) * 64 + kk * 32 + g * 8);
            #pragma unroll
            for (int i = 0; i < 4; ++i)
                #pragma unroll
                for (int j = 0; j < 4; ++j)
                    acc[i][j] = __builtin_amdgcn_mfma_f32_16x16x32_bf16(af[i], bf[j], acc[i][j], 0, 0, 0);
        }
    }

    #pragma unroll
    for (int i = 0; i < 4; ++i)
        #pragma unroll
        for (int r = 0; r < 4; ++r) {
            const int row = m0 + wr * 64 + i * 16 + g * 4 + r;
            #pragma unroll
            for (int j = 0; j < 4; ++j) {
                const int col = n0 + wc * 64 + j * 16 + c;
                const float v = acc[i][j][r];
                if (BF16OUT) ((short*)Cv)[(size_t)row * ldc + col] = f2bf(v);
                else         ((float*)Cv)[(size_t)row * ldc + col] = v;
            }
        }
}

// ---------------------------------------------------------------------------
// In-place cos-scale + axial RoPE on bf16 q and k (unchanged).
// ---------------------------------------------------------------------------
__global__ __launch_bounds__(256) void transform_qk(
    short* __restrict__ qkv, const float* __restrict__ pos,
    const float* __restrict__ scale, const float* __restrict__ freqs)
{
    const int w    = threadIdx.x >> 6;
    const int lane = threadIdx.x & 63;
    const int rid  = blockIdx.x * 4 + w;
    const int l    = rid >> 4;
    const int h    = rid & 15;

    short* qp = qkv + (size_t)l * QKVN + h * DHEAD;
    short* kp = qp + DMODEL;

    float q = bf2f(qp[lane]);
    float k = bf2f(kp[lane]);

    float sq = q * q, sk = k * k;
    #pragma unroll
    for (int o = 32; o > 0; o >>= 1) {
        sq += __shfl_xor(sq, o);
        sk += __shfl_xor(sk, o);
    }
    const float ss = sqrtf(fabsf(scale[h]) + 1e-8f);
    q *= ss * rsqrtf(sq + 1e-8f);
    k *= ss * rsqrtf(sk + 1e-8f);

    const int   j  = lane & 31;
    const float p  = pos[l * 2 + (j < 16 ? 1 : 0)];
    const float fj = (j < 16) ? freqs[256 + h * 16 + j] : freqs[h * 16 + (j - 16)];
    const float th = (p * 2.0f - 1.0f) * fj;
    const float cs = cosf(th), sn = sinf(th);

    const float qo = __shfl_xor(q, 32);
    const float ko = __shfl_xor(k, 32);
    const float qr = (lane < 32) ? q * cs - qo * sn : q * cs + qo * sn;
    const float kr = (lane < 32) ? k * cs - ko * sn : k * cs + ko * sn;

    qp[lane] = f2bf(qr);
    kp[lane] = f2bf(kr);
}

// ---------------------------------------------------------------------------
// Fused flash attention, 4 waves x 16 q rows = 64 q rows / block, KVBLK=64.
// grid = (144, 16):
//   x   0..47 : query chunks  (16 qb x 3 splits, 16 tiles each)
//   x  48..95 : causal qt 47..32, NS=3 (11..16 tiles)
//   x 96..127 : causal qt 31..16, NS=2 (8..16 tiles)
//   x128..143 : causal qt 15..0,  NS=1 direct (16..1 tiles)
// Split-0 partials go unnormalized into attn (+pml0); extra splits into slot
// arrays pacc/pml (64-row slots). K via global_load_lds (pre-swizzled source,
// double-buffered), V reg-staged pair-packed, P via cvt_pk -> LDS scratch.
// ---------------------------------------------------------------------------
__global__ __launch_bounds__(256) void attn_fused(
    const short* __restrict__ qkv, short* __restrict__ attn,
    short* __restrict__ pacc_c, float* __restrict__ pml_c, float* __restrict__ pml0_c,
    short* __restrict__ pacc_q, float* __restrict__ pml_q, float* __restrict__ pml0_q)
{
    __shared__ short Kl[2][64 * 64];
    __shared__ short VTl[2][64 * 64];
    __shared__ short Pl[4][16 * 64];

    const int h = blockIdx.y;
    const int t = threadIdx.x, lane = t & 63, w = t >> 6;
    const int c = lane & 15, g = lane >> 4;
    const int qcol = h * DHEAD, kcol = DMODEL + h * DHEAD, vcol = 2 * DMODEL + h * DHEAD;

    // ---- decode chunk ----
    const int xc = blockIdx.x;
    bool causal; int z, NS, q0, kt0, ktn, qt = 0, qb = 0;
    if (xc < 48) {
        causal = false; qb = xc / 3; z = xc - qb * 3; NS = 3;
        q0 = SPOKES + qb * 64; kt0 = z * 16; ktn = 16;
    } else {
        causal = true;
        if (xc < 96)       { const int i = xc - 48; qt = 47 - i / 3; z = i - (i / 3) * 3; NS = 3; }
        else if (xc < 128) { const int i = xc - 96; qt = 31 - (i >> 1); z = i & 1; NS = 2; }
        else               { qt = 143 - xc; z = 0; NS = 1; }
        q0 = qt * 64;
        const int full = qt + 1, b = full / NS, r = full - b * NS;
        kt0 = z * b + (z < r ? z : r);
        ktn = b + (z < r ? 1 : 0);
    }

    const int qg = q0 + w * 16 + c;       // this lane's q row

    bf16x8 qf0, qf1;
    {
        const short* qrow = qkv + (size_t)qg * QKVN + qcol;
        qf0 = *(const bf16x8*)(qrow + g * 8);
        qf1 = *(const bf16x8*)(qrow + 32 + g * 8);
    }

    float m = -INFINITY, l = 0.0f;
    f32x4 acc[4] = {};
    bf16x8 vregA, vregB;

    // ---- staging helpers ----
    auto KDMA = [&](int buf, int kt) {
        const int k0 = kt * 64;
        #pragma unroll
        for (int i = 0; i < 2; ++i) {
            const int ch = i * 256 + t;                 // 16B chunk index
            const int kv = ch >> 3, s = ch & 7;
            const int o = s ^ ((kv & 7) ^ (kv >> 3));   // pre-swizzled source octet
            gload_lds16(qkv + (size_t)(k0 + kv) * QKVN + kcol + o * 8,
                        (char*)Kl[buf] + i * 4096 + w * 1024);
        }
    };
    // thread t owns kv pair {2*(t>>3), 2*(t>>3)+1} x d-octet (t&7)
    auto VLOAD = [&](int kt) {
        const int k0 = kt * 64;
        const short* v0 = qkv + (size_t)(k0 + 2 * (t >> 3)) * QKVN + vcol + (t & 7) * 8;
        vregA = *(const bf16x8*)v0;
        vregB = *(const bf16x8*)(v0 + QKVN);
    };
    auto VWRITE = [&](int buf) {
        const int p2 = t >> 3, oc = t & 7;
        #pragma unroll
        for (int j = 0; j < 8; ++j) {
            const int d = oc * 8 + j;
            const unsigned u = ((unsigned)(unsigned short)vregA[j]) |
                               (((unsigned)(unsigned short)vregB[j]) << 16);
            *(unsigned*)((char*)VTl[buf] + d * 128 + ((4 * p2) ^ swz(d))) = u;
        }
    };

    // ---- prologue: stage tile kt0 into buffer 0 ----
    VLOAD(kt0);
    KDMA(0, kt0);
    VWRITE(0);
    __syncthreads();

    for (int it = 0; it < ktn; ++it) {
        const int kt = kt0 + it;
        const int cur = it & 1, nxt = cur ^ 1;
        const int k0 = kt * 64;

        if (it + 1 < ktn) { VLOAD(kt + 1); KDMA(nxt, kt + 1); }   // async prefetch

        // ---- S^T = K . Q^T  (one 16-q fragment per wave) ----
        f32x4 st[4];
        #pragma unroll
        for (int mt = 0; mt < 4; ++mt) {
            const int kvr = mt * 16 + c;
            bf16x8 ka = *(const bf16x8*)((const char*)Kl[cur] + kvr * 128 + ((g * 16) ^ swz(kvr)));
            bf16x8 kb = *(const bf16x8*)((const char*)Kl[cur] + kvr * 128 + ((64 + g * 16) ^ swz(kvr)));
            f32x4 zz = {0.f, 0.f, 0.f, 0.f};
            zz = __builtin_amdgcn_mfma_f32_16x16x32_bf16(ka, qf0, zz, 0, 0, 0);
            st[mt] = __builtin_amdgcn_mfma_f32_16x16x32_bf16(kb, qf1, zz, 0, 0, 0);
        }

        // ---- online softmax (defer-max); P -> per-wave LDS scratch ----
        if (causal && (k0 + 63 > q0 + w * 16)) {
            #pragma unroll
            for (int mt = 0; mt < 4; ++mt)
                #pragma unroll
                for (int r = 0; r < 4; ++r)
                    if (k0 + mt * 16 + g * 4 + r > qg) st[mt][r] = -INFINITY;
        }
        float tmax = -INFINITY;
        #pragma unroll
        for (int mt = 0; mt < 4; ++mt)
            #pragma unroll
            for (int r = 0; r < 4; ++r) tmax = fmaxf(tmax, st[mt][r]);
        tmax = fmaxf(tmax, __shfl_xor(tmax, 16));
        tmax = fmaxf(tmax, __shfl_xor(tmax, 32));
        if (__any(tmax > m + 8.0f)) {             // rescale only on real max growth
            const float mnew = fmaxf(m, tmax);
            const float pfac = __expf(m - mnew);
            l *= pfac;
            #pragma unroll
            for (int dt = 0; dt < 4; ++dt)
                #pragma unroll
                for (int r = 0; r < 4; ++r) acc[dt][r] *= pfac;
            m = mnew;
        }
        {
            const float mref = m;
            float rs = 0.0f;
            #pragma unroll
            for (int mt = 0; mt < 4; ++mt) {
                const float e0 = __expf(st[mt][0] - mref);
                const float e1 = __expf(st[mt][1] - mref);
                const float e2 = __expf(st[mt][2] - mref);
                const float e3 = __expf(st[mt][3] - mref);
                rs += (e0 + e1) + (e2 + e3);
                uint2 u;
                u.x = cvt_pk_bf16(e0, e1);
                u.y = cvt_pk_bf16(e2, e3);
                *(uint2*)((char*)Pl[w] + c * 128 + ((mt * 32 + g * 8) ^ swz(c))) = u;
            }
            rs += __shfl_xor(rs, 16);
            rs += __shfl_xor(rs, 32);
            l += rs;
        }

        // ---- PV: out^T += V^T . P^T ----
        #pragma unroll
        for (int kc = 0; kc < 2; ++kc) {
            bf16x8 pb = *(const bf16x8*)((const char*)Pl[w] + c * 128 + ((kc * 64 + g * 16) ^ swz(c)));
            #pragma unroll
            for (int dt = 0; dt < 4; ++dt) {
                const int d = dt * 16 + c;
                bf16x8 vf = *(const bf16x8*)((const char*)VTl[cur] + d * 128 + ((kc * 64 + g * 16) ^ swz(d)));
                acc[dt] = __builtin_amdgcn_mfma_f32_16x16x32_bf16(vf, pb, acc[dt], 0, 0, 0);
            }
        }

        if (it + 1 < ktn) VWRITE(nxt);    // reg data arrived during compute
        __syncthreads();                  // drains KDMA; all readers done with cur
    }

    // ---- epilogue ----
    if (!causal && z == 0) {
        // fold in the self term (split 0 only)
        float ss = 0.0f;
        {
            const short* krow = qkv + (size_t)qg * QKVN + kcol;
            bf16x8 k0s = *(const bf16x8*)(krow + g * 8);
            bf16x8 k1s = *(const bf16x8*)(krow + 32 + g * 8);
            #pragma unroll
            for (int j = 0; j < 8; ++j)
                ss += bf2f(qf0[j]) * bf2f(k0s[j]) + bf2f(qf1[j]) * bf2f(k1s[j]);
            ss += __shfl_xor(ss, 16);
            ss += __shfl_xor(ss, 32);
        }
        const float mnew = fmaxf(m, ss);
        const float pf = __expf(m - mnew);
        const float ps = __expf(ss - mnew);
        const short* vrow = qkv + (size_t)qg * QKVN + vcol;
        #pragma unroll
        for (int dt = 0; dt < 4; ++dt) {
            bf16x4 vs = *(const bf16x4*)(vrow + dt * 16 + g * 4);
            #pragma unroll
            for (int r = 0; r < 4; ++r)
                acc[dt][r] = acc[dt][r] * pf + ps * bf2f(vs[r]);
        }
        l = l * pf + ps;
        m = mnew;
    }

    if (causal && NS == 1) {
        // direct normalized write
        const float inv = 1.0f / l;
        short* orow = attn + (size_t)qg * DMODEL + qcol;
        #pragma unroll
        for (int dt = 0; dt < 4; ++dt)
            #pragma unroll
            for (int r = 0; r < 4; ++r)
                orow[dt * 16 + g * 4 + r] = f2bf(acc[dt][r] * inv);
    } else if (z == 0) {
        // split-0 partial: unnormalized into attn + (m,l) into pml0
        float* pml0 = causal ? pml0_c : pml0_q;
        const int stride = causal ? 2048 : 1024;
        const int base   = causal ? 1024 : SPOKES;
        short* orow = attn + (size_t)qg * DMODEL + qcol;
        #pragma unroll
        for (int dt = 0; dt < 4; ++dt)
            #pragma unroll
            for (int r = 0; r < 4; ++r)
                orow[dt * 16 + g * 4 + r] = f2bf(acc[dt][r]);
        if (g == 0) {
            float* p = pml0 + ((size_t)h * stride + (qg - base)) * 2;
            p[0] = m;
            p[1] = l;
        }
    } else {
        // extra-split partial into slot arrays (64-row slots)
        const int slot = causal ? (qt < 32 ? qt - 16 : 16 + (qt - 32) * 2 + (z - 1))
                                : qb * 2 + (z - 1);
        short* pacc = causal ? pacc_c : pacc_q;
        float* pml  = causal ? pml_c  : pml_q;
        const int rl = w * 16 + c;            // row within 64-row block
        short* prow = pacc + ((size_t)slot * 64 + rl) * DMODEL + qcol;
        #pragma unroll
        for (int dt = 0; dt < 4; ++dt)
            #pragma unroll
            for (int r = 0; r < 4; ++r)
                prow[dt * 16 + g * 4 + r] = f2bf(acc[dt][r]);
        if (g == 0) {
            float* p = pml + ((size_t)(slot * 16 + h) * 64 + rl) * 2;
            p[0] = m;
            p[1] = l;
        }
    }
}

// ---------------------------------------------------------------------------
// Combine: attn row (split-0, unnormalized, with pml0) + nextra slot partials.
// slot(r, e) = slotBase + (r>>6)*slotMul + e     (64-row slots)
// ---------------------------------------------------------------------------
__global__ __launch_bounds__(256) void attn_combine(
    short* __restrict__ attn, const float* __restrict__ pml0,
    const short* __restrict__ pacc, const float* __restrict__ pml,
    int rowbase, int pml0_stride, int pml0_off,
    int slotBase, int slotMul, int nextra)
{
    const int i = blockIdx.x * 256 + threadIdx.x;   // nrows * NH * 8 threads
    const int r = i >> 7;
    const int h = (i >> 3) & 15;
    const int o = i & 7;

    const float* p0 = pml0 + ((size_t)h * pml0_stride + pml0_off + r) * 2;
    const float m0 = p0[0], l0 = p0[1];
    float M = m0;
    float me[2], le[2];
    for (int e = 0; e < nextra; ++e) {
        const int slot = slotBase + (r >> 6) * slotMul + e;
        const float* p = pml + ((size_t)(slot * 16 + h) * 64 + (r & 63)) * 2;
        me[e] = p[0]; le[e] = p[1];
        M = fmaxf(M, me[e]);
    }
    const float w0 = __expf(m0 - M);
    float L = w0 * l0;
    float we[2];
    for (int e = 0; e < nextra; ++e) { we[e] = __expf(me[e] - M); L += we[e] * le[e]; }

    short* arow = attn + (size_t)(rowbase + r) * DMODEL + h * 64 + o * 8;
    bf16x8 a0 = *(const bf16x8*)arow;
    float outv[8];
    #pragma unroll
    for (int j = 0; j < 8; ++j) outv[j] = w0 * bf2f(a0[j]);
    for (int e = 0; e < nextra; ++e) {
        const int slot = slotBase + (r >> 6) * slotMul + e;
        bf16x8 a = *(const bf16x8*)(pacc + ((size_t)slot * 64 + (r & 63)) * DMODEL + h * 64 + o * 8);
        #pragma unroll
        for (int j = 0; j < 8; ++j) outv[j] += we[e] * bf2f(a[j]);
    }
    const float inv = 1.0f / L;
    bf16x8 res;
    #pragma unroll
    for (int j = 0; j < 8; ++j) res[j] = f2bf(outv[j] * inv);
    *(bf16x8*)arow = res;
}

// ---------------------------------------------------------------------------
extern "C" void kernel_launch(void* const* d_in, const int* in_sizes, int n_in,
                              void* d_out, int out_size, void* d_ws, size_t ws_size,
                              hipStream_t stream)
{
    const float* x      = (const float*)d_in[0];
    const float* pos    = (const float*)d_in[1];
    const float* qkv_w  = (const float*)d_in[2];
    const float* out_w  = (const float*)d_in[3];
    const float* scale  = (const float*)d_in[4];
    const float* freqs  = (const float*)d_in[5];
    float*       out    = (float*)d_out;

    const size_t MB = 1024 * 1024;
    char* ws = (char*)d_ws;
    short* qkv_bf  = (short*)(ws);                       // [0,24MB)  qkv (live)
    short* x_bf    = (short*)(ws + 24 * MB);             // [24,32)   x -> attn (alias)
    short* wqkv_bf = (short*)(ws + 32 * MB);             // [32,38)   qkv_w -> query partials
    short* wout_bf = (short*)(ws + 38 * MB);             // [38,40)   out_w (live)
    short* pacc_c  = (short*)(ws + 40 * MB);             // [40,46)   48 slots x 64 x 1024 bf16 = 6MB
    float* pml_c   = (float*)(ws + 46 * MB);             // 393216 B  (48 slots x 16h x 64 x 2)
    float* pml0_c  = (float*)(ws + 46 * MB + 393216);    // 262144 B  (ends ~46.63MB)
    short* attn_bf = x_bf;                               // alias (x dead after gemm1)
    short* pacc_q  = wqkv_bf;                            // 32 slots x 64 x 1024 bf16 = 4MB
    float* pml_q   = (float*)((char*)wqkv_bf + 4194304); // 262144 B
    float* pml0_q  = (float*)((char*)wqkv_bf + 4456448); // 131072 B (ends ~36.4MB)

    const dim3 blk(256);

    cvt_f32_bf16<<<dim3(SEQL * DMODEL / 8 / 256), blk, 0, stream>>>(x, x_bf, SEQL * DMODEL / 8);
    cvt_f32_bf16<<<dim3(QKVN * DMODEL / 8 / 256), blk, 0, stream>>>(qkv_w, wqkv_bf, QKVN * DMODEL / 8);
    cvt_f32_bf16<<<dim3(DMODEL * DMODEL / 8 / 256), blk, 0, stream>>>(out_w, wout_bf, DMODEL * DMODEL / 8);

    // 1) qkv = x @ qkv_w^T  (bf16 in, bf16 out)
    gemm_bf16<true><<<dim3(QKVN / 128, SEQL / 128), blk, 0, stream>>>(
        x_bf, wqkv_bf, qkv_bf, DMODEL, QKVN);

    // 2) cos-scale + axial rope on q,k (in place, bf16)
    transform_qk<<<dim3(SEQL * NH / 4), blk, 0, stream>>>(qkv_bf, pos, scale, freqs);

    // 3) fused attention, uniform <=16-tile chunks at 64-q granularity
    attn_fused<<<dim3(144, NH), blk, 0, stream>>>(
        qkv_bf, attn_bf, pacc_c, pml_c, pml0_c, pacc_q, pml_q, pml0_q);

    // 4) combines: causal qt16..31 (1 extra), qt32..47 (2 extra), query (2 extra)
    attn_combine<<<dim3(512), blk, 0, stream>>>(attn_bf, pml0_c, pacc_c, pml_c,
                                                1024, 2048, 0,    0, 1, 1);
    attn_combine<<<dim3(512), blk, 0, stream>>>(attn_bf, pml0_c, pacc_c, pml_c,
                                                2048, 2048, 1024, 16, 2, 2);
    attn_combine<<<dim3(512), blk, 0, stream>>>(attn_bf, pml0_q, pacc_q, pml_q,
                                                SPOKES, 1024, 0,  0, 2, 2);

    // 5) out = attn @ out_w^T  (bf16 in, f32 out)
    gemm_bf16<false><<<dim3(DMODEL / 128, SEQL / 128), blk, 0, stream>>>(
        attn_bf, wout_bf, out, DMODEL, DMODEL);
}